// Round 1
// baseline (496.012 us; speedup 1.0000x reference)
//
#include <hip/hip_runtime.h>
#include <math.h>

#define N_NODES 50000
#define E_EDGES 800000
#define F_IN    128
#define F_MID   256
#define F_OUT   128

// ---------------- workspace layout (bytes) ----------------
// A  (h1 [50000,256] fp32, later reused as h2 [50000,128]) : 51,200,000
// B  (gelu output  [50000,256] fp32)                       : 51,200,000
// dinv  [50000] f32, hist [50000] i32, rp [50001] i32,
// cursor[50000] i32, csr_src [E] i32, csr_norm [E] f32
#define A_OFF     0
#define B_OFF     51200000UL
#define DINV_OFF  102400000UL
#define HIST_OFF  102600000UL
#define RP_OFF    102800000UL
#define CUR_OFF   103000320UL
#define CSRS_OFF  103200512UL
#define CSRN_OFF  106400512UL
// total ~109.6 MB

__global__ __launch_bounds__(256) void init_hist(int* __restrict__ hist, int n) {
  int i = blockIdx.x * 256 + threadIdx.x;
  if (i < n) hist[i] = 0;
}

__global__ __launch_bounds__(256) void hist_kernel(const int* __restrict__ dst,
                                                   int* __restrict__ hist, int e) {
  int i = blockIdx.x * 256 + threadIdx.x;
  if (i < e) atomicAdd(&hist[dst[i]], 1);
}

__global__ __launch_bounds__(256) void dinv_kernel(const int* __restrict__ hist,
                                                   float* __restrict__ dinv, int n) {
  int i = blockIdx.x * 256 + threadIdx.x;
  if (i < n) dinv[i] = rsqrtf((float)(hist[i] + 1));  // +1 self loop
}

// single-block exclusive scan of hist -> rp[0..n], cursor copy
__global__ __launch_bounds__(1024) void scan_kernel(const int* __restrict__ hist,
                                                    int* __restrict__ rp,
                                                    int* __restrict__ cursor, int n) {
  __shared__ int wsum[17];
  __shared__ int carry_s;
  int tid = threadIdx.x, lane = tid & 63, wv = tid >> 6;
  if (tid == 0) carry_s = 0;
  __syncthreads();
  int nIter = (n + 4095) / 4096;
  for (int it = 0; it < nIter; ++it) {
    int i0 = it * 4096 + tid * 4;
    int4 v = make_int4(0, 0, 0, 0);
    if (i0 + 3 < n) {
      v = *reinterpret_cast<const int4*>(hist + i0);
    } else {
      if (i0 < n)     v.x = hist[i0];
      if (i0 + 1 < n) v.y = hist[i0 + 1];
      if (i0 + 2 < n) v.z = hist[i0 + 2];
    }
    int s = v.x + v.y + v.z + v.w;
    int sc = s;
    #pragma unroll
    for (int m = 1; m < 64; m <<= 1) {
      int o = __shfl_up(sc, m);
      if (lane >= m) sc += o;
    }
    if (lane == 63) wsum[wv] = sc;
    __syncthreads();
    if (tid == 0) {
      int run = 0;
      for (int w = 0; w < 16; ++w) { int t = wsum[w]; wsum[w] = run; run += t; }
      wsum[16] = run;
    }
    __syncthreads();
    int base = carry_s + wsum[wv] + (sc - s);
    if (i0 < n)     { rp[i0] = base;                 cursor[i0] = base; }
    if (i0 + 1 < n) { int b1_ = base + v.x;          rp[i0+1] = b1_; cursor[i0+1] = b1_; }
    if (i0 + 2 < n) { int b2_ = base + v.x + v.y;    rp[i0+2] = b2_; cursor[i0+2] = b2_; }
    if (i0 + 3 < n) { int b3_ = base + v.x + v.y + v.z; rp[i0+3] = b3_; cursor[i0+3] = b3_; }
    __syncthreads();            // everyone has read carry_s
    if (tid == 0) carry_s += wsum[16];
    __syncthreads();
  }
  if (tid == 0) rp[n] = carry_s;
}

__global__ __launch_bounds__(256) void fill_kernel(const int* __restrict__ src,
                                                   const int* __restrict__ dst,
                                                   const float* __restrict__ dinv,
                                                   int* __restrict__ cursor,
                                                   int* __restrict__ csr_src,
                                                   float* __restrict__ csr_norm, int e) {
  int i = blockIdx.x * 256 + threadIdx.x;
  if (i < e) {
    int s = src[i], d = dst[i];
    int pos = atomicAdd(&cursor[d], 1);
    csr_src[pos] = s;
    csr_norm[pos] = dinv[s] * dinv[d];
  }
}

// LN(x[128]) @ W1[128,256] -> out[50000,256].  16 rows/block, 256 threads.
__global__ __launch_bounds__(256) void ln_gemm1(const float* __restrict__ x,
                                                const float* __restrict__ W,
                                                const float* __restrict__ gam,
                                                const float* __restrict__ bet,
                                                float* __restrict__ out) {
  __shared__ float xn[16][132];
  int t = threadIdx.x;
  int row = t >> 4, sub = t & 15;
  size_t grow = (size_t)blockIdx.x * 16 + row;
  const float4* xp = reinterpret_cast<const float4*>(x + grow * 128 + sub * 8);
  float4 a0 = xp[0], a1 = xp[1];
  float v[8] = {a0.x, a0.y, a0.z, a0.w, a1.x, a1.y, a1.z, a1.w};
  float s = 0.f, sq = 0.f;
  #pragma unroll
  for (int j = 0; j < 8; ++j) { s += v[j]; sq += v[j] * v[j]; }
  #pragma unroll
  for (int m = 1; m < 16; m <<= 1) { s += __shfl_xor(s, m); sq += __shfl_xor(sq, m); }
  float mu = s * (1.0f / 128.0f);
  float var = sq * (1.0f / 128.0f) - mu * mu;
  float rs = rsqrtf(var + 1e-5f);
  #pragma unroll
  for (int j = 0; j < 8; ++j) {
    int f = sub * 8 + j;
    xn[row][f] = (v[j] - mu) * rs * gam[f] + bet[f];
  }
  __syncthreads();
  int lane = t & 63, wv = t >> 6;
  int cb = lane * 4, rb = wv * 4;
  float acc[4][4];
  #pragma unroll
  for (int i = 0; i < 4; ++i)
    #pragma unroll
    for (int j = 0; j < 4; ++j) acc[i][j] = 0.f;
  #pragma unroll 4
  for (int k = 0; k < 128; ++k) {
    float4 w4 = *reinterpret_cast<const float4*>(W + k * 256 + cb);
    #pragma unroll
    for (int i = 0; i < 4; ++i) {
      float a = xn[rb + i][k];
      acc[i][0] += a * w4.x; acc[i][1] += a * w4.y;
      acc[i][2] += a * w4.z; acc[i][3] += a * w4.w;
    }
  }
  size_t obase = ((size_t)blockIdx.x * 16 + rb) * 256 + cb;
  #pragma unroll
  for (int i = 0; i < 4; ++i) {
    float4 o = make_float4(acc[i][0], acc[i][1], acc[i][2], acc[i][3]);
    *reinterpret_cast<float4*>(out + obase + (size_t)i * 256) = o;
  }
}

// LN(g[256]) @ W4[256,128] -> out[50000,128]
__global__ __launch_bounds__(256) void ln_gemm2(const float* __restrict__ xg,
                                                const float* __restrict__ W,
                                                const float* __restrict__ gam,
                                                const float* __restrict__ bet,
                                                float* __restrict__ out) {
  __shared__ float xn[16][260];
  int t = threadIdx.x;
  int row = t >> 4, sub = t & 15;
  size_t grow = (size_t)blockIdx.x * 16 + row;
  const float4* xp = reinterpret_cast<const float4*>(xg + grow * 256 + sub * 16);
  float4 a0 = xp[0], a1 = xp[1], a2 = xp[2], a3 = xp[3];
  float v[16] = {a0.x,a0.y,a0.z,a0.w, a1.x,a1.y,a1.z,a1.w,
                 a2.x,a2.y,a2.z,a2.w, a3.x,a3.y,a3.z,a3.w};
  float s = 0.f, sq = 0.f;
  #pragma unroll
  for (int j = 0; j < 16; ++j) { s += v[j]; sq += v[j] * v[j]; }
  #pragma unroll
  for (int m = 1; m < 16; m <<= 1) { s += __shfl_xor(s, m); sq += __shfl_xor(sq, m); }
  float mu = s * (1.0f / 256.0f);
  float var = sq * (1.0f / 256.0f) - mu * mu;
  float rs = rsqrtf(var + 1e-5f);
  #pragma unroll
  for (int j = 0; j < 16; ++j) {
    int f = sub * 16 + j;
    xn[row][f] = (v[j] - mu) * rs * gam[f] + bet[f];
  }
  __syncthreads();
  int lane = t & 63, wv = t >> 6;
  int cb = lane * 2, rb = wv * 4;
  float acc[4][2];
  #pragma unroll
  for (int i = 0; i < 4; ++i) { acc[i][0] = 0.f; acc[i][1] = 0.f; }
  #pragma unroll 4
  for (int k = 0; k < 256; ++k) {
    float2 w2 = *reinterpret_cast<const float2*>(W + k * 128 + cb);
    #pragma unroll
    for (int i = 0; i < 4; ++i) {
      float a = xn[rb + i][k];
      acc[i][0] += a * w2.x; acc[i][1] += a * w2.y;
    }
  }
  size_t obase = ((size_t)blockIdx.x * 16 + rb) * 128 + cb;
  #pragma unroll
  for (int i = 0; i < 4; ++i) {
    float2 o = make_float2(acc[i][0], acc[i][1]);
    *reinterpret_cast<float2*>(out + obase + (size_t)i * 128) = o;
  }
}

// aggregate layer1: out[i,:] = sum_e h[src_e,:]*norm_e + h[i,:]*dinv[i]^2 + b1, then exact GELU
__global__ __launch_bounds__(256) void agg1(const float* __restrict__ h,
                                            const int* __restrict__ rp,
                                            const int* __restrict__ csr_src,
                                            const float* __restrict__ csr_norm,
                                            const float* __restrict__ dinv,
                                            const float* __restrict__ b,
                                            float* __restrict__ out) {
  int lane = threadIdx.x & 63, wv = threadIdx.x >> 6;
  int node = blockIdx.x * 4 + wv;
  int c = lane * 4;
  float di = dinv[node];
  float sn = di * di;
  float4 hv = *reinterpret_cast<const float4*>(h + (size_t)node * 256 + c);
  float ax = hv.x * sn, ay = hv.y * sn, az = hv.z * sn, aw = hv.w * sn;
  int e0 = rp[node], e1 = rp[node + 1];
  for (int e = e0; e < e1; ++e) {
    int sidx = csr_src[e];
    float nr = csr_norm[e];
    float4 g4 = *reinterpret_cast<const float4*>(h + (size_t)sidx * 256 + c);
    ax += g4.x * nr; ay += g4.y * nr; az += g4.z * nr; aw += g4.w * nr;
  }
  float4 bb = *reinterpret_cast<const float4*>(b + c);
  ax += bb.x; ay += bb.y; az += bb.z; aw += bb.w;
  const float k = 0.70710678118654752f;
  ax = 0.5f * ax * (1.f + erff(ax * k));
  ay = 0.5f * ay * (1.f + erff(ay * k));
  az = 0.5f * az * (1.f + erff(az * k));
  aw = 0.5f * aw * (1.f + erff(aw * k));
  *reinterpret_cast<float4*>(out + (size_t)node * 256 + c) = make_float4(ax, ay, az, aw);
}

// aggregate layer2: out[i,:] = sum_e h[src_e,:]*norm_e + h[i,:]*dinv[i]^2 + b4
__global__ __launch_bounds__(256) void agg2(const float* __restrict__ h,
                                            const int* __restrict__ rp,
                                            const int* __restrict__ csr_src,
                                            const float* __restrict__ csr_norm,
                                            const float* __restrict__ dinv,
                                            const float* __restrict__ b,
                                            float* __restrict__ out) {
  int lane = threadIdx.x & 63, wv = threadIdx.x >> 6;
  int node = blockIdx.x * 4 + wv;
  int c = lane * 2;
  float di = dinv[node];
  float sn = di * di;
  float2 hv = *reinterpret_cast<const float2*>(h + (size_t)node * 128 + c);
  float ax = hv.x * sn, ay = hv.y * sn;
  int e0 = rp[node], e1 = rp[node + 1];
  for (int e = e0; e < e1; ++e) {
    int sidx = csr_src[e];
    float nr = csr_norm[e];
    float2 g2 = *reinterpret_cast<const float2*>(h + (size_t)sidx * 128 + c);
    ax += g2.x * nr; ay += g2.y * nr;
  }
  float2 bb = *reinterpret_cast<const float2*>(b + c);
  ax += bb.x; ay += bb.y;
  *reinterpret_cast<float2*>(out + (size_t)node * 128 + c) = make_float2(ax, ay);
}

extern "C" void kernel_launch(void* const* d_in, const int* in_sizes, int n_in,
                              void* d_out, int out_size, void* d_ws, size_t ws_size,
                              hipStream_t stream) {
  (void)in_sizes; (void)n_in; (void)out_size; (void)ws_size;
  const float* x   = (const float*)d_in[0];
  const float* W1  = (const float*)d_in[1];
  const float* b1  = (const float*)d_in[2];
  const float* g1  = (const float*)d_in[3];
  const float* be1 = (const float*)d_in[4];
  const float* W4  = (const float*)d_in[5];
  const float* b4  = (const float*)d_in[6];
  const float* g4  = (const float*)d_in[7];
  const float* be4 = (const float*)d_in[8];
  const int*   ei  = (const int*)d_in[9];
  const int* src = ei;             // edge_index[0]
  const int* dst = ei + E_EDGES;   // edge_index[1]

  char* ws = (char*)d_ws;
  float* A        = (float*)(ws + A_OFF);      // h1, later h2
  float* B        = (float*)(ws + B_OFF);      // gelu output
  float* dinv     = (float*)(ws + DINV_OFF);
  int*   hist     = (int*)(ws + HIST_OFF);
  int*   rp       = (int*)(ws + RP_OFF);
  int*   cursor   = (int*)(ws + CUR_OFF);
  int*   csr_src  = (int*)(ws + CSRS_OFF);
  float* csr_norm = (float*)(ws + CSRN_OFF);
  float* outp     = (float*)d_out;

  int nblkN = (N_NODES + 255) / 256;
  int nblkE = (E_EDGES + 255) / 256;

  hipLaunchKernelGGL(init_hist, dim3(nblkN), dim3(256), 0, stream, hist, N_NODES);
  hipLaunchKernelGGL(hist_kernel, dim3(nblkE), dim3(256), 0, stream, dst, hist, E_EDGES);
  hipLaunchKernelGGL(dinv_kernel, dim3(nblkN), dim3(256), 0, stream, hist, dinv, N_NODES);
  hipLaunchKernelGGL(scan_kernel, dim3(1), dim3(1024), 0, stream, hist, rp, cursor, N_NODES);
  hipLaunchKernelGGL(fill_kernel, dim3(nblkE), dim3(256), 0, stream,
                     src, dst, dinv, cursor, csr_src, csr_norm, E_EDGES);

  hipLaunchKernelGGL(ln_gemm1, dim3(N_NODES / 16), dim3(256), 0, stream, x, W1, g1, be1, A);
  hipLaunchKernelGGL(agg1, dim3(N_NODES / 4), dim3(256), 0, stream,
                     A, rp, csr_src, csr_norm, dinv, b1, B);
  hipLaunchKernelGGL(ln_gemm2, dim3(N_NODES / 16), dim3(256), 0, stream, B, W4, g4, be4, A);
  hipLaunchKernelGGL(agg2, dim3(N_NODES / 4), dim3(256), 0, stream,
                     A, rp, csr_src, csr_norm, dinv, b4, outp);
}

// Round 2
// 324.581 us; speedup vs baseline: 1.5282x; 1.5282x over previous
//
#include <hip/hip_runtime.h>
#include <math.h>

#define N_NODES 50000
#define E_EDGES 800000

// ---------------- workspace layout (bytes) ----------------
// T1  bf16 [50000,128] gather table L1 (reused as T2 later)   : 12.8 MB @ 0
// AGG1 fp32 [50000,128] (reused as T2b bf16 [50000,256])      : 25.6 MB @ 12.8M
// G   fp32 [50000,256] gelu output                            : 51.2 MB @ 38.4M
// dinv/hist/rp/cursor/csr/bsum                                : @ 89.6M+
#define T1_OFF    0UL
#define AGG1_OFF  12800000UL
#define G_OFF     38400000UL
#define T2B_OFF   AGG1_OFF     // alias: AGG1 dead after gemm1
#define T2_OFF    T1_OFF       // alias: T1 dead after agg1
#define DINV_OFF  89600000UL
#define HIST_OFF  89800000UL
#define RP_OFF    90000000UL
#define CUR_OFF   90200064UL
#define CSR_OFF   90400128UL
#define BSUM_OFF  96800128UL
// total ~96.8 MB

__device__ __forceinline__ float lo16f(unsigned u) { return __uint_as_float(u << 16); }
__device__ __forceinline__ float hi16f(unsigned u) { return __uint_as_float(u & 0xffff0000u); }
__device__ __forceinline__ unsigned pack2bf(float a, float b) {
  unsigned ua = __float_as_uint(a); ua += 0x7fffu + ((ua >> 16) & 1u);
  unsigned ub = __float_as_uint(b); ub += 0x7fffu + ((ub >> 16) & 1u);
  return (ua >> 16) | (ub & 0xffff0000u);
}
__device__ __forceinline__ float gelu_f(float x) {
  return 0.5f * x * (1.f + erff(x * 0.70710678118654752f));
}

__global__ __launch_bounds__(256) void init_hist(int* __restrict__ hist, int n) {
  int i = blockIdx.x * 256 + threadIdx.x;
  if (i < n) hist[i] = 0;
}

__global__ __launch_bounds__(256) void hist_kernel(const int* __restrict__ dst,
                                                   int* __restrict__ hist, int e) {
  int i = blockIdx.x * 256 + threadIdx.x;
  if (i < e) atomicAdd(&hist[dst[i]], 1);
}

__global__ __launch_bounds__(256) void dinv_kernel(const int* __restrict__ hist,
                                                   float* __restrict__ dinv, int n) {
  int i = blockIdx.x * 256 + threadIdx.x;
  if (i < n) dinv[i] = rsqrtf((float)(hist[i] + 1));  // +1 self loop
}

// ---- 3-kernel multi-block exclusive scan: hist -> rp[0..n], cursor ----
__global__ __launch_bounds__(1024) void scan_partial(const int* __restrict__ hist,
                                                     int* __restrict__ rp,
                                                     int* __restrict__ bsum, int n) {
  __shared__ int wsum[16];
  int tid = threadIdx.x, lane = tid & 63, wv = tid >> 6;
  int i = blockIdx.x * 1024 + tid;
  int v = (i < n) ? hist[i] : 0;
  int sc = v;
  #pragma unroll
  for (int m = 1; m < 64; m <<= 1) { int o = __shfl_up(sc, m); if (lane >= m) sc += o; }
  if (lane == 63) wsum[wv] = sc;
  __syncthreads();
  if (wv == 0) {
    int w = (lane < 16) ? wsum[lane] : 0;
    int swc = w;
    #pragma unroll
    for (int m = 1; m < 16; m <<= 1) { int o = __shfl_up(swc, m); if (lane >= m) swc += o; }
    if (lane < 16) wsum[lane] = swc - w;       // exclusive wave offsets
    if (lane == 15) bsum[blockIdx.x] = swc;    // block total
  }
  __syncthreads();
  if (i < n) rp[i] = (sc - v) + wsum[wv];
}

__global__ __launch_bounds__(64) void scan_bsums(int* __restrict__ bsum, int nb) {
  int lane = threadIdx.x;
  int v = (lane < nb) ? bsum[lane] : 0;
  int sc = v;
  #pragma unroll
  for (int m = 1; m < 64; m <<= 1) { int o = __shfl_up(sc, m); if (lane >= m) sc += o; }
  if (lane < nb) bsum[lane] = sc - v;          // exclusive
  if (lane == 63) bsum[nb] = sc;               // grand total
}

__global__ __launch_bounds__(1024) void scan_add(int* __restrict__ rp,
                                                 int* __restrict__ cursor,
                                                 const int* __restrict__ bsum, int n) {
  int i = blockIdx.x * 1024 + threadIdx.x;
  if (i < n) {
    int v = rp[i] + bsum[blockIdx.x];
    rp[i] = v; cursor[i] = v;
  }
  if (i == 0) rp[n] = bsum[gridDim.x];
}

__global__ __launch_bounds__(256) void fill_kernel(const int* __restrict__ src,
                                                   const int* __restrict__ dst,
                                                   const float* __restrict__ dinv,
                                                   int* __restrict__ cursor,
                                                   int2* __restrict__ csr, int e) {
  int i = blockIdx.x * 256 + threadIdx.x;
  if (i < e) {
    int s = src[i], d = dst[i];
    int pos = atomicAdd(&cursor[d], 1);
    csr[pos] = make_int2(s, __float_as_int(dinv[s] * dinv[d]));
  }
}

// LN over 128, write bf16 table. One wave per row.
__global__ __launch_bounds__(256) void ln1_kernel(const float* __restrict__ x,
                                                  const float* __restrict__ g,
                                                  const float* __restrict__ be,
                                                  unsigned* __restrict__ T) {
  int lane = threadIdx.x & 63, wv = threadIdx.x >> 6;
  int row = blockIdx.x * 4 + wv;
  float2 v = *reinterpret_cast<const float2*>(x + (size_t)row * 128 + lane * 2);
  float s = v.x + v.y, sq = v.x * v.x + v.y * v.y;
  #pragma unroll
  for (int m = 1; m < 64; m <<= 1) { s += __shfl_xor(s, m); sq += __shfl_xor(sq, m); }
  float mu = s * (1.f / 128.f);
  float var = sq * (1.f / 128.f) - mu * mu;
  float rs = rsqrtf(var + 1e-5f);
  float2 gg = *reinterpret_cast<const float2*>(g + lane * 2);
  float2 bb = *reinterpret_cast<const float2*>(be + lane * 2);
  float o0 = (v.x - mu) * rs * gg.x + bb.x;
  float o1 = (v.y - mu) * rs * gg.y + bb.y;
  T[(size_t)row * 64 + lane] = pack2bf(o0, o1);
}

// LN over 256, write bf16 table. One wave per row.
__global__ __launch_bounds__(256) void ln2_kernel(const float* __restrict__ G,
                                                  const float* __restrict__ g,
                                                  const float* __restrict__ be,
                                                  unsigned* __restrict__ T2b) {
  int lane = threadIdx.x & 63, wv = threadIdx.x >> 6;
  int row = blockIdx.x * 4 + wv;
  float4 v = *reinterpret_cast<const float4*>(G + (size_t)row * 256 + lane * 4);
  float s = v.x + v.y + v.z + v.w;
  float sq = v.x * v.x + v.y * v.y + v.z * v.z + v.w * v.w;
  #pragma unroll
  for (int m = 1; m < 64; m <<= 1) { s += __shfl_xor(s, m); sq += __shfl_xor(sq, m); }
  float mu = s * (1.f / 256.f);
  float var = sq * (1.f / 256.f) - mu * mu;
  float rs = rsqrtf(var + 1e-5f);
  float4 gg = *reinterpret_cast<const float4*>(g + lane * 4);
  float4 bb = *reinterpret_cast<const float4*>(be + lane * 4);
  uint2 p;
  p.x = pack2bf((v.x - mu) * rs * gg.x + bb.x, (v.y - mu) * rs * gg.y + bb.y);
  p.y = pack2bf((v.z - mu) * rs * gg.z + bb.z, (v.w - mu) * rs * gg.w + bb.w);
  *reinterpret_cast<uint2*>(T2b + (size_t)row * 128 + lane * 2) = p;
}

// 128-wide aggregation from bf16 table. One wave per node, 4-way unrolled edges.
template <bool BIAS>
__global__ __launch_bounds__(256) void agg128(const unsigned* __restrict__ T,
                                              const int* __restrict__ rp,
                                              const int2* __restrict__ csr,
                                              const float* __restrict__ dinv,
                                              const float* __restrict__ b,
                                              float* __restrict__ out) {
  int lane = threadIdx.x & 63, wv = threadIdx.x >> 6;
  int node = blockIdx.x * 4 + wv;
  float di = dinv[node], sn = di * di;
  unsigned us = T[(size_t)node * 64 + lane];
  float a0 = lo16f(us) * sn, a1 = hi16f(us) * sn;
  int e = rp[node], e1 = rp[node + 1];
  for (; e + 3 < e1; e += 4) {
    int2 c0 = csr[e], c1 = csr[e + 1], c2 = csr[e + 2], c3 = csr[e + 3];
    unsigned u0 = T[(size_t)c0.x * 64 + lane];
    unsigned u1 = T[(size_t)c1.x * 64 + lane];
    unsigned u2 = T[(size_t)c2.x * 64 + lane];
    unsigned u3 = T[(size_t)c3.x * 64 + lane];
    float n0 = __int_as_float(c0.y), n1 = __int_as_float(c1.y);
    float n2 = __int_as_float(c2.y), n3 = __int_as_float(c3.y);
    a0 += lo16f(u0) * n0; a1 += hi16f(u0) * n0;
    a0 += lo16f(u1) * n1; a1 += hi16f(u1) * n1;
    a0 += lo16f(u2) * n2; a1 += hi16f(u2) * n2;
    a0 += lo16f(u3) * n3; a1 += hi16f(u3) * n3;
  }
  for (; e < e1; ++e) {
    int2 c = csr[e];
    unsigned u = T[(size_t)c.x * 64 + lane];
    float nr = __int_as_float(c.y);
    a0 += lo16f(u) * nr; a1 += hi16f(u) * nr;
  }
  if (BIAS) {
    float2 bb = *reinterpret_cast<const float2*>(b + lane * 2);
    a0 += bb.x; a1 += bb.y;
  }
  *reinterpret_cast<float2*>(out + (size_t)node * 128 + lane * 2) = make_float2(a0, a1);
}

// [n,128] fp32 @ W[128,256] + b, exact GELU -> [n,256] fp32. 32 rows/block.
__global__ __launch_bounds__(256) void gemm1_gelu(const float* __restrict__ A,
                                                  const float* __restrict__ W,
                                                  const float* __restrict__ b,
                                                  float* __restrict__ out, int n) {
  __shared__ float xn[32 * 128];
  int t = threadIdx.x;
  size_t base = (size_t)blockIdx.x * 32 * 128;
  #pragma unroll
  for (int i = 0; i < 4; ++i) {
    int f = i * 256 + t;  // float4 index, linear: contiguous across lanes
    float4 v = *reinterpret_cast<const float4*>(A + base + (size_t)f * 4);
    *reinterpret_cast<float4*>(xn + f * 4) = v;
  }
  __syncthreads();
  int lane = t & 63, wv = t >> 6;
  int cb = lane * 4, rb = wv * 8;
  float acc[8][4];
  #pragma unroll
  for (int i = 0; i < 8; ++i)
    #pragma unroll
    for (int j = 0; j < 4; ++j) acc[i][j] = 0.f;
  #pragma unroll 2
  for (int k = 0; k < 128; ++k) {
    float4 w4 = *reinterpret_cast<const float4*>(W + k * 256 + cb);
    #pragma unroll
    for (int i = 0; i < 8; ++i) {
      float a = xn[(rb + i) * 128 + k];
      acc[i][0] += a * w4.x; acc[i][1] += a * w4.y;
      acc[i][2] += a * w4.z; acc[i][3] += a * w4.w;
    }
  }
  float4 bb = *reinterpret_cast<const float4*>(b + cb);
  int row0 = blockIdx.x * 32 + rb;
  #pragma unroll
  for (int i = 0; i < 8; ++i) {
    int r = row0 + i;
    if (r < n) {
      float4 o;
      o.x = gelu_f(acc[i][0] + bb.x); o.y = gelu_f(acc[i][1] + bb.y);
      o.z = gelu_f(acc[i][2] + bb.z); o.w = gelu_f(acc[i][3] + bb.w);
      *reinterpret_cast<float4*>(out + (size_t)r * 256 + cb) = o;
    }
  }
}

// [n,256] bf16 @ W[256,128] -> bf16 [n,64 uints]. 32 rows/block. No bias (added in agg2).
__global__ __launch_bounds__(256) void gemm2_k(const unsigned* __restrict__ T2b,
                                               const float* __restrict__ W,
                                               unsigned* __restrict__ T2, int n) {
  __shared__ float xn[32 * 256];
  int t = threadIdx.x;
  size_t base = (size_t)blockIdx.x * 32 * 128;  // uint units
  #pragma unroll
  for (int i = 0; i < 8; ++i) {
    int u = i * 256 + t;  // uint2 index, linear
    uint2 v = *reinterpret_cast<const uint2*>(T2b + base + (size_t)u * 2);
    float4 f;
    f.x = lo16f(v.x); f.y = hi16f(v.x); f.z = lo16f(v.y); f.w = hi16f(v.y);
    *reinterpret_cast<float4*>(xn + u * 4) = f;
  }
  __syncthreads();
  int lane = t & 63, wv = t >> 6;
  int cb = lane * 2, rb = wv * 8;
  float acc[8][2];
  #pragma unroll
  for (int i = 0; i < 8; ++i) { acc[i][0] = 0.f; acc[i][1] = 0.f; }
  #pragma unroll 2
  for (int k = 0; k < 256; ++k) {
    float2 w2 = *reinterpret_cast<const float2*>(W + k * 128 + cb);
    #pragma unroll
    for (int i = 0; i < 8; ++i) {
      float a = xn[(rb + i) * 256 + k];
      acc[i][0] += a * w2.x; acc[i][1] += a * w2.y;
    }
  }
  int row0 = blockIdx.x * 32 + rb;
  #pragma unroll
  for (int i = 0; i < 8; ++i) {
    int r = row0 + i;
    if (r < n) T2[(size_t)r * 64 + lane] = pack2bf(acc[i][0], acc[i][1]);
  }
}

extern "C" void kernel_launch(void* const* d_in, const int* in_sizes, int n_in,
                              void* d_out, int out_size, void* d_ws, size_t ws_size,
                              hipStream_t stream) {
  (void)in_sizes; (void)n_in; (void)out_size; (void)ws_size;
  const float* x   = (const float*)d_in[0];
  const float* W1  = (const float*)d_in[1];
  const float* b1  = (const float*)d_in[2];
  const float* g1  = (const float*)d_in[3];
  const float* be1 = (const float*)d_in[4];
  const float* W4  = (const float*)d_in[5];
  const float* b4  = (const float*)d_in[6];
  const float* g4  = (const float*)d_in[7];
  const float* be4 = (const float*)d_in[8];
  const int*   ei  = (const int*)d_in[9];
  const int* src = ei;
  const int* dst = ei + E_EDGES;

  char* ws = (char*)d_ws;
  unsigned* T1   = (unsigned*)(ws + T1_OFF);
  float*    AGG1 = (float*)(ws + AGG1_OFF);
  float*    G    = (float*)(ws + G_OFF);
  unsigned* T2b  = (unsigned*)(ws + T2B_OFF);
  unsigned* T2   = (unsigned*)(ws + T2_OFF);
  float* dinv    = (float*)(ws + DINV_OFF);
  int*   hist    = (int*)(ws + HIST_OFF);
  int*   rp      = (int*)(ws + RP_OFF);
  int*   cursor  = (int*)(ws + CUR_OFF);
  int2*  csr     = (int2*)(ws + CSR_OFF);
  int*   bsum    = (int*)(ws + BSUM_OFF);
  float* outp    = (float*)d_out;

  int nblkN = (N_NODES + 255) / 256;
  int nblkE = (E_EDGES + 255) / 256;
  int nbScan = (N_NODES + 1023) / 1024;   // 49
  int nblkG = (N_NODES + 31) / 32;        // 1563

  hipLaunchKernelGGL(init_hist, dim3(nblkN), dim3(256), 0, stream, hist, N_NODES);
  hipLaunchKernelGGL(hist_kernel, dim3(nblkE), dim3(256), 0, stream, dst, hist, E_EDGES);
  hipLaunchKernelGGL(dinv_kernel, dim3(nblkN), dim3(256), 0, stream, hist, dinv, N_NODES);
  hipLaunchKernelGGL(scan_partial, dim3(nbScan), dim3(1024), 0, stream, hist, rp, bsum, N_NODES);
  hipLaunchKernelGGL(scan_bsums, dim3(1), dim3(64), 0, stream, bsum, nbScan);
  hipLaunchKernelGGL(scan_add, dim3(nbScan), dim3(1024), 0, stream, rp, cursor, bsum, N_NODES);
  hipLaunchKernelGGL(fill_kernel, dim3(nblkE), dim3(256), 0, stream,
                     src, dst, dinv, cursor, csr, E_EDGES);

  // Layer 1: LN -> aggregate(128) -> GEMM(128->256)+bias+GELU
  hipLaunchKernelGGL(ln1_kernel, dim3(N_NODES / 4), dim3(256), 0, stream, x, g1, be1, T1);
  hipLaunchKernelGGL(agg128<false>, dim3(N_NODES / 4), dim3(256), 0, stream,
                     T1, rp, csr, dinv, (const float*)nullptr, AGG1);
  hipLaunchKernelGGL(gemm1_gelu, dim3(nblkG), dim3(256), 0, stream, AGG1, W1, b1, G, N_NODES);

  // Layer 2: LN -> GEMM(256->128) -> aggregate(128)+bias
  hipLaunchKernelGGL(ln2_kernel, dim3(N_NODES / 4), dim3(256), 0, stream, G, g4, be4, T2b);
  hipLaunchKernelGGL(gemm2_k, dim3(nblkG), dim3(256), 0, stream, T2b, W4, T2, N_NODES);
  hipLaunchKernelGGL(agg128<true>, dim3(N_NODES / 4), dim3(256), 0, stream,
                     T2, rp, csr, dinv, b4, outp);
}

// Round 4
// 250.510 us; speedup vs baseline: 1.9800x; 1.2957x over previous
//
#include <hip/hip_runtime.h>
#include <math.h>

#define N_NODES 50000
#define E_EDGES 800000

typedef __attribute__((ext_vector_type(4))) float f32x4;
typedef __attribute__((ext_vector_type(8))) short s16x8;

// ---------------- workspace layout (bytes) ----------------
#define T1_OFF    0UL          // bf16 [50000,128] gather table L1; reused as T2 later (12.8 MB)
#define AGG1_OFF  12800000UL   // fp32 [50000,128] aggregated LN1(x) (25.6 MB), dead after gemm1
#define T2B_OFF   38400000UL   // bf16 [50000,256] LN2 output (25.6 MB)
#define WB1H_OFF  64000000UL   // W1 B-frag bf16 hi (64 KB)
#define WB1L_OFF  64100096UL   // W1 B-frag bf16 lo
#define WB4H_OFF  64200192UL   // W4 B-frag bf16 hi
#define WB4L_OFF  64300288UL   // W4 B-frag bf16 lo
#define DINV_OFF  64400384UL
#define HIST_OFF  64600576UL
#define RP_OFF    64800768UL
#define CUR_OFF   65001088UL
#define CSR_OFF   65201408UL   // int2 [E] (6.4 MB)
#define BSUM_OFF  71601408UL

__device__ __forceinline__ float lo16f(unsigned u) { return __uint_as_float(u << 16); }
__device__ __forceinline__ float hi16f(unsigned u) { return __uint_as_float(u & 0xffff0000u); }
__device__ __forceinline__ unsigned pack2bf(float a, float b) {
  unsigned ua = __float_as_uint(a); ua += 0x7fffu + ((ua >> 16) & 1u);
  unsigned ub = __float_as_uint(b); ub += 0x7fffu + ((ub >> 16) & 1u);
  return (ua >> 16) | (ub & 0xffff0000u);
}
__device__ __forceinline__ float gelu_f(float x) {
  return 0.5f * x * (1.f + erff(x * 0.70710678118654752f));
}

__global__ __launch_bounds__(256) void init_hist(int* __restrict__ hist, int n) {
  int i = blockIdx.x * 256 + threadIdx.x;
  if (i < n) hist[i] = 0;
}

__global__ __launch_bounds__(256) void hist_kernel(const int* __restrict__ dst,
                                                   int* __restrict__ hist, int e) {
  int i = blockIdx.x * 256 + threadIdx.x;
  if (i < e) atomicAdd(&hist[dst[i]], 1);
}

__global__ __launch_bounds__(256) void dinv_kernel(const int* __restrict__ hist,
                                                   float* __restrict__ dinv, int n) {
  int i = blockIdx.x * 256 + threadIdx.x;
  if (i < n) dinv[i] = rsqrtf((float)(hist[i] + 1));  // +1 self loop
}

// ---- multi-block exclusive scan: hist -> rp[0..n], cursor ----
__global__ __launch_bounds__(1024) void scan_partial(const int* __restrict__ hist,
                                                     int* __restrict__ rp,
                                                     int* __restrict__ bsum, int n) {
  __shared__ int wsum[16];
  int tid = threadIdx.x, lane = tid & 63, wv = tid >> 6;
  int i = blockIdx.x * 1024 + tid;
  int v = (i < n) ? hist[i] : 0;
  int sc = v;
  #pragma unroll
  for (int m = 1; m < 64; m <<= 1) { int o = __shfl_up(sc, m); if (lane >= m) sc += o; }
  if (lane == 63) wsum[wv] = sc;
  __syncthreads();
  if (wv == 0) {
    int w = (lane < 16) ? wsum[lane] : 0;
    int swc = w;
    #pragma unroll
    for (int m = 1; m < 16; m <<= 1) { int o = __shfl_up(swc, m); if (lane >= m) swc += o; }
    if (lane < 16) wsum[lane] = swc - w;
    if (lane == 15) bsum[blockIdx.x] = swc;
  }
  __syncthreads();
  if (i < n) rp[i] = (sc - v) + wsum[wv];
}

__global__ __launch_bounds__(64) void scan_bsums(int* __restrict__ bsum, int nb) {
  int lane = threadIdx.x;
  int v = (lane < nb) ? bsum[lane] : 0;
  int sc = v;
  #pragma unroll
  for (int m = 1; m < 64; m <<= 1) { int o = __shfl_up(sc, m); if (lane >= m) sc += o; }
  if (lane < nb) bsum[lane] = sc - v;
  if (lane == 63) bsum[nb] = sc;
}

__global__ __launch_bounds__(1024) void scan_add(int* __restrict__ rp,
                                                 int* __restrict__ cursor,
                                                 const int* __restrict__ bsum, int n) {
  int i = blockIdx.x * 1024 + threadIdx.x;
  if (i < n) {
    int v = rp[i] + bsum[blockIdx.x];
    rp[i] = v; cursor[i] = v;
  }
  if (i == 0) rp[n] = bsum[gridDim.x];
}

__global__ __launch_bounds__(256) void fill_kernel(const int* __restrict__ src,
                                                   const int* __restrict__ dst,
                                                   const float* __restrict__ dinv,
                                                   int* __restrict__ cursor,
                                                   int2* __restrict__ csr, int e) {
  int i = blockIdx.x * 256 + threadIdx.x;
  if (i < e) {
    int s = src[i], d = dst[i];
    int pos = atomicAdd(&cursor[d], 1);
    csr[pos] = make_int2(s, __float_as_int(dinv[s] * dinv[d]));
  }
}

// W[K][N] fp32 -> B-frag bf16 hi+lo: flat tid = ((nt*KS+ks)*4+kg)*16 + c15, uint4 per tid.
__global__ __launch_bounds__(256) void convW_split(const float* __restrict__ W,
                                                   unsigned* __restrict__ Wh,
                                                   unsigned* __restrict__ Wl, int K, int N) {
  int tid = blockIdx.x * 256 + threadIdx.x;
  if (tid >= (K * N) / 8) return;
  int c15 = tid & 15;
  int kg  = (tid >> 4) & 3;
  int KS  = K >> 5;
  int ks  = (tid >> 6) % KS;
  int nt  = (tid >> 6) / KS;
  int col = nt * 16 + c15;
  int k0  = ks * 32 + kg * 8;
  float w[8];
  #pragma unroll
  for (int j = 0; j < 8; ++j) w[j] = W[(size_t)(k0 + j) * N + col];
  uint4 h, l;
  h.x = pack2bf(w[0], w[1]); l.x = pack2bf(w[0] - lo16f(h.x), w[1] - hi16f(h.x));
  h.y = pack2bf(w[2], w[3]); l.y = pack2bf(w[2] - lo16f(h.y), w[3] - hi16f(h.y));
  h.z = pack2bf(w[4], w[5]); l.z = pack2bf(w[4] - lo16f(h.z), w[5] - hi16f(h.z));
  h.w = pack2bf(w[6], w[7]); l.w = pack2bf(w[6] - lo16f(h.w), w[7] - hi16f(h.w));
  *reinterpret_cast<uint4*>(Wh + (size_t)tid * 4) = h;
  *reinterpret_cast<uint4*>(Wl + (size_t)tid * 4) = l;
}

// LN over 128, write bf16 table. One wave per row.
__global__ __launch_bounds__(256) void ln1_kernel(const float* __restrict__ x,
                                                  const float* __restrict__ g,
                                                  const float* __restrict__ be,
                                                  unsigned* __restrict__ T) {
  int lane = threadIdx.x & 63, wv = threadIdx.x >> 6;
  int row = blockIdx.x * 4 + wv;
  float2 v = *reinterpret_cast<const float2*>(x + (size_t)row * 128 + lane * 2);
  float s = v.x + v.y, sq = v.x * v.x + v.y * v.y;
  #pragma unroll
  for (int m = 1; m < 64; m <<= 1) { s += __shfl_xor(s, m); sq += __shfl_xor(sq, m); }
  float mu = s * (1.f / 128.f);
  float var = sq * (1.f / 128.f) - mu * mu;
  float rs = rsqrtf(var + 1e-5f);
  float2 gg = *reinterpret_cast<const float2*>(g + lane * 2);
  float2 bb = *reinterpret_cast<const float2*>(be + lane * 2);
  T[(size_t)row * 64 + lane] =
      pack2bf((v.x - mu) * rs * gg.x + bb.x, (v.y - mu) * rs * gg.y + bb.y);
}

// 128-wide aggregation from bf16 table. One wave per node.
// MODE 0: write fp32 (no bias)   MODE 1: write bf16 table (no bias)
// MODE 2: write fp32 d_out (+bias)
template <int MODE>
__global__ __launch_bounds__(256) void agg128(const unsigned* __restrict__ T,
                                              const int* __restrict__ rp,
                                              const int2* __restrict__ csr,
                                              const float* __restrict__ dinv,
                                              const float* __restrict__ b,
                                              void* __restrict__ outv) {
  int lane = threadIdx.x & 63, wv = threadIdx.x >> 6;
  int node = blockIdx.x * 4 + wv;
  float di = dinv[node], sn = di * di;
  unsigned us = T[(size_t)node * 64 + lane];
  float a0 = lo16f(us) * sn, a1 = hi16f(us) * sn;
  int e = rp[node], e1 = rp[node + 1];
  for (; e + 3 < e1; e += 4) {
    int4 ca = *reinterpret_cast<const int4*>(&csr[e]);
    int4 cb = *reinterpret_cast<const int4*>(&csr[e + 2]);
    unsigned u0 = T[(size_t)ca.x * 64 + lane];
    unsigned u1 = T[(size_t)ca.z * 64 + lane];
    unsigned u2 = T[(size_t)cb.x * 64 + lane];
    unsigned u3 = T[(size_t)cb.z * 64 + lane];
    float n0 = __int_as_float(ca.y), n1 = __int_as_float(ca.w);
    float n2 = __int_as_float(cb.y), n3 = __int_as_float(cb.w);
    a0 += lo16f(u0) * n0; a1 += hi16f(u0) * n0;
    a0 += lo16f(u1) * n1; a1 += hi16f(u1) * n1;
    a0 += lo16f(u2) * n2; a1 += hi16f(u2) * n2;
    a0 += lo16f(u3) * n3; a1 += hi16f(u3) * n3;
  }
  for (; e < e1; ++e) {
    int2 c = csr[e];
    unsigned u = T[(size_t)c.x * 64 + lane];
    float nr = __int_as_float(c.y);
    a0 += lo16f(u) * nr; a1 += hi16f(u) * nr;
  }
  if (MODE == 0) {
    *reinterpret_cast<float2*>((float*)outv + (size_t)node * 128 + lane * 2) =
        make_float2(a0, a1);
  } else if (MODE == 1) {
    ((unsigned*)outv)[(size_t)node * 64 + lane] = pack2bf(a0, a1);
  } else {
    float2 bb = *reinterpret_cast<const float2*>(b + lane * 2);
    *reinterpret_cast<float2*>((float*)outv + (size_t)node * 128 + lane * 2) =
        make_float2(a0 + bb.x, a1 + bb.y);
  }
}

// MFMA GEMM1: fp32[n,128] (split hi/lo) @ (Wb1h+Wb1l) -> +bias, GELU, LN2 -> bf16 [n,256].
__global__ __launch_bounds__(256) void gemm1_fused(const float* __restrict__ A,
                                                   const unsigned* __restrict__ Wh,
                                                   const unsigned* __restrict__ Wl,
                                                   const float* __restrict__ b,
                                                   const float* __restrict__ g,
                                                   const float* __restrict__ be,
                                                   unsigned* __restrict__ T2b, int n) {
  __shared__ float st[32 * 260];
  int t = threadIdx.x, lane = t & 63, w = t >> 6;
  int rtile = (w >> 1) * 16;             // 0 or 16 (block-relative)
  int c0 = (w & 1) * 128;                // 0 or 128
  int arow = blockIdx.x * 32 + rtile + (lane & 15);
  if (arow >= n) arow = n - 1;
  const float* aptr = A + (size_t)arow * 128 + (lane >> 4) * 8;
  f32x4 acc[8];
  #pragma unroll
  for (int nf = 0; nf < 8; ++nf) acc[nf] = (f32x4)(0.f);
  #pragma unroll
  for (int ks = 0; ks < 4; ++ks) {
    float4 v0 = *reinterpret_cast<const float4*>(aptr + ks * 32);
    float4 v1 = *reinterpret_cast<const float4*>(aptr + ks * 32 + 4);
    uint4 h, l;
    h.x = pack2bf(v0.x, v0.y); l.x = pack2bf(v0.x - lo16f(h.x), v0.y - hi16f(h.x));
    h.y = pack2bf(v0.z, v0.w); l.y = pack2bf(v0.z - lo16f(h.y), v0.w - hi16f(h.y));
    h.z = pack2bf(v1.x, v1.y); l.z = pack2bf(v1.x - lo16f(h.z), v1.y - hi16f(h.z));
    h.w = pack2bf(v1.z, v1.w); l.w = pack2bf(v1.z - lo16f(h.w), v1.w - hi16f(h.w));
    s16x8 ah = *reinterpret_cast<s16x8*>(&h);
    s16x8 al = *reinterpret_cast<s16x8*>(&l);
    #pragma unroll
    for (int nf = 0; nf < 8; ++nf) {
      int nt = (c0 >> 4) + nf;
      size_t bo = (size_t)(((nt * 4 + ks) * 4 + (lane >> 4)) * 16 + (lane & 15)) * 4;
      s16x8 bh = *reinterpret_cast<const s16x8*>(Wh + bo);
      s16x8 bl = *reinterpret_cast<const s16x8*>(Wl + bo);
      acc[nf] = __builtin_amdgcn_mfma_f32_16x16x32_bf16(ah, bh, acc[nf], 0, 0, 0);
      acc[nf] = __builtin_amdgcn_mfma_f32_16x16x32_bf16(al, bh, acc[nf], 0, 0, 0);
      acc[nf] = __builtin_amdgcn_mfma_f32_16x16x32_bf16(ah, bl, acc[nf], 0, 0, 0);
    }
  }
  // bias + GELU -> LDS (fp32)
  #pragma unroll
  for (int nf = 0; nf < 8; ++nf) {
    int col = c0 + nf * 16 + (lane & 15);
    float bb = b[col];
    #pragma unroll
    for (int r = 0; r < 4; ++r) {
      int row = rtile + (lane >> 4) * 4 + r;
      st[row * 260 + col] = gelu_f(acc[nf][r] + bb);
    }
  }
  __syncthreads();
  // LN over each 256-row; wave w handles rows w*8 .. w*8+7
  float4 gg = *reinterpret_cast<const float4*>(g + lane * 4);
  float4 bb2 = *reinterpret_cast<const float4*>(be + lane * 4);
  #pragma unroll
  for (int rr = 0; rr < 8; ++rr) {
    int row = w * 8 + rr;
    float4 v = *reinterpret_cast<const float4*>(&st[row * 260 + lane * 4]);
    float s = v.x + v.y + v.z + v.w;
    float sq = v.x * v.x + v.y * v.y + v.z * v.z + v.w * v.w;
    #pragma unroll
    for (int m = 1; m < 64; m <<= 1) { s += __shfl_xor(s, m); sq += __shfl_xor(sq, m); }
    float mu = s * (1.f / 256.f);
    float var = sq * (1.f / 256.f) - mu * mu;
    float rs = rsqrtf(var + 1e-5f);
    int gr = blockIdx.x * 32 + row;
    if (gr < n) {
      uint2 p;
      p.x = pack2bf((v.x - mu) * rs * gg.x + bb2.x, (v.y - mu) * rs * gg.y + bb2.y);
      p.y = pack2bf((v.z - mu) * rs * gg.z + bb2.z, (v.w - mu) * rs * gg.w + bb2.w);
      *reinterpret_cast<uint2*>(T2b + (size_t)gr * 128 + lane * 2) = p;
    }
  }
}

// MFMA GEMM2: bf16[n,256] @ (Wb4h+Wb4l) -> bf16 table [n,128] (bias deferred to agg2).
__global__ __launch_bounds__(256) void gemm2_mfma(const unsigned* __restrict__ Ab,
                                                  const unsigned* __restrict__ Wh,
                                                  const unsigned* __restrict__ Wl,
                                                  unsigned* __restrict__ T2, int n) {
  __shared__ float st[32 * 132];
  int t = threadIdx.x, lane = t & 63, w = t >> 6;
  int rtile = (w >> 1) * 16;
  int c0 = (w & 1) * 64;
  int arow = blockIdx.x * 32 + rtile + (lane & 15);
  if (arow >= n) arow = n - 1;
  const unsigned* aptr = Ab + (size_t)arow * 128 + (lane >> 4) * 4;
  f32x4 acc[4];
  #pragma unroll
  for (int nf = 0; nf < 4; ++nf) acc[nf] = (f32x4)(0.f);
  #pragma unroll
  for (int ks = 0; ks < 8; ++ks) {
    s16x8 af = *reinterpret_cast<const s16x8*>(aptr + ks * 16);
    #pragma unroll
    for (int nf = 0; nf < 4; ++nf) {
      int nt = (c0 >> 4) + nf;
      size_t bo = (size_t)(((nt * 8 + ks) * 4 + (lane >> 4)) * 16 + (lane & 15)) * 4;
      s16x8 bh = *reinterpret_cast<const s16x8*>(Wh + bo);
      s16x8 bl = *reinterpret_cast<const s16x8*>(Wl + bo);
      acc[nf] = __builtin_amdgcn_mfma_f32_16x16x32_bf16(af, bh, acc[nf], 0, 0, 0);
      acc[nf] = __builtin_amdgcn_mfma_f32_16x16x32_bf16(af, bl, acc[nf], 0, 0, 0);
    }
  }
  #pragma unroll
  for (int nf = 0; nf < 4; ++nf) {
    int col = c0 + nf * 16 + (lane & 15);
    #pragma unroll
    for (int r = 0; r < 4; ++r) {
      int row = rtile + (lane >> 4) * 4 + r;
      st[row * 132 + col] = acc[nf][r];
    }
  }
  __syncthreads();
  #pragma unroll
  for (int rr = 0; rr < 8; ++rr) {
    int row = w * 8 + rr;
    int gr = blockIdx.x * 32 + row;
    if (gr < n) {
      float2 v = *reinterpret_cast<const float2*>(&st[row * 132 + lane * 2]);
      T2[(size_t)gr * 64 + lane] = pack2bf(v.x, v.y);
    }
  }
}

extern "C" void kernel_launch(void* const* d_in, const int* in_sizes, int n_in,
                              void* d_out, int out_size, void* d_ws, size_t ws_size,
                              hipStream_t stream) {
  (void)in_sizes; (void)n_in; (void)out_size; (void)ws_size;
  const float* x   = (const float*)d_in[0];
  const float* W1  = (const float*)d_in[1];
  const float* b1  = (const float*)d_in[2];
  const float* g1  = (const float*)d_in[3];
  const float* be1 = (const float*)d_in[4];
  const float* W4  = (const float*)d_in[5];
  const float* b4  = (const float*)d_in[6];
  const float* g4  = (const float*)d_in[7];
  const float* be4 = (const float*)d_in[8];
  const int*   ei  = (const int*)d_in[9];
  const int* src = ei;
  const int* dst = ei + E_EDGES;

  char* ws = (char*)d_ws;
  unsigned* T1    = (unsigned*)(ws + T1_OFF);
  unsigned* T2    = (unsigned*)(ws + T1_OFF);      // alias: T1 dead after gemm1
  float*    AGG1  = (float*)(ws + AGG1_OFF);
  unsigned* T2b   = (unsigned*)(ws + T2B_OFF);
  unsigned* Wb1h  = (unsigned*)(ws + WB1H_OFF);
  unsigned* Wb1l  = (unsigned*)(ws + WB1L_OFF);
  unsigned* Wb4h  = (unsigned*)(ws + WB4H_OFF);
  unsigned* Wb4l  = (unsigned*)(ws + WB4L_OFF);
  float* dinv     = (float*)(ws + DINV_OFF);
  int*   hist     = (int*)(ws + HIST_OFF);
  int*   rp       = (int*)(ws + RP_OFF);
  int*   cursor   = (int*)(ws + CUR_OFF);
  int2*  csr      = (int2*)(ws + CSR_OFF);
  int*   bsum     = (int*)(ws + BSUM_OFF);
  float* outp     = (float*)d_out;

  int nblkN = (N_NODES + 255) / 256;
  int nblkE = (E_EDGES + 255) / 256;
  int nbScan = (N_NODES + 1023) / 1024;
  int nblkG = (N_NODES + 31) / 32;  // 1563

  hipLaunchKernelGGL(init_hist, dim3(nblkN), dim3(256), 0, stream, hist, N_NODES);
  hipLaunchKernelGGL(hist_kernel, dim3(nblkE), dim3(256), 0, stream, dst, hist, E_EDGES);
  hipLaunchKernelGGL(dinv_kernel, dim3(nblkN), dim3(256), 0, stream, hist, dinv, N_NODES);
  hipLaunchKernelGGL(scan_partial, dim3(nbScan), dim3(1024), 0, stream, hist, rp, bsum, N_NODES);
  hipLaunchKernelGGL(scan_bsums, dim3(1), dim3(64), 0, stream, bsum, nbScan);
  hipLaunchKernelGGL(scan_add, dim3(nbScan), dim3(1024), 0, stream, rp, cursor, bsum, N_NODES);
  hipLaunchKernelGGL(fill_kernel, dim3(nblkE), dim3(256), 0, stream,
                     src, dst, dinv, cursor, csr, E_EDGES);
  hipLaunchKernelGGL(convW_split, dim3(16), dim3(256), 0, stream, W1, Wb1h, Wb1l, 128, 256);
  hipLaunchKernelGGL(convW_split, dim3(16), dim3(256), 0, stream, W4, Wb4h, Wb4l, 256, 128);

  // Layer 1: LN -> aggregate(128) fp32 -> MFMA GEMM(split) + bias + GELU + LN2 (fused)
  hipLaunchKernelGGL(ln1_kernel, dim3(N_NODES / 4), dim3(256), 0, stream, x, g1, be1, T1);
  hipLaunchKernelGGL(agg128<0>, dim3(N_NODES / 4), dim3(256), 0, stream,
                     T1, rp, csr, dinv, (const float*)nullptr, (void*)AGG1);
  hipLaunchKernelGGL(gemm1_fused, dim3(nblkG), dim3(256), 0, stream,
                     AGG1, Wb1h, Wb1l, b1, g4, be4, T2b, N_NODES);

  // Layer 2: MFMA GEMM(W-split) -> aggregate(128)+bias -> out
  hipLaunchKernelGGL(gemm2_mfma, dim3(nblkG), dim3(256), 0, stream, T2b, Wb4h, Wb4l, T2, N_NODES);
  hipLaunchKernelGGL(agg128<2>, dim3(N_NODES / 4), dim3(256), 0, stream,
                     T2, rp, csr, dinv, b4, (void*)outp);
}

// Round 5
// 233.988 us; speedup vs baseline: 2.1198x; 1.0706x over previous
//
#include <hip/hip_runtime.h>
#include <math.h>

#define N_NODES 50000
#define E_EDGES 800000

typedef __attribute__((ext_vector_type(4))) float f32x4;
typedef __attribute__((ext_vector_type(8))) short s16x8;

// ---------------- workspace layout (bytes) ----------------
#define T1_OFF    0UL          // bf16 [50000,128] L1 gather table; reused as T2 after gemm1
#define AGG1_OFF  12800000UL   // fp32 [50000,128] aggregated LN1(x) (25.6 MB)
#define T2B_OFF   38400000UL   // bf16 [50000,256] LN2 output (25.6 MB)
#define WB1H_OFF  64000000UL   // W1 B-frag bf16 hi (64 KB)
#define WB1L_OFF  64100096UL
#define WB4H_OFF  64200192UL
#define WB4L_OFF  64300288UL
#define DINV_OFF  64400384UL   // fp32 [50000]
#define HIST8_OFF 64600384UL   // int [50000*8] seg-sharded histogram (1.6 MB)
#define RP8_OFF   66200384UL   // int [50000*8 + 1]
#define POSREL_OFF 67800448UL  // int [E] per-edge rank within (dst,seg) bucket
#define CSRS_OFF  71000448UL   // int [E] src-sorted-by-dst
#define BSUM_OFF  74200448UL

__device__ __forceinline__ float lo16f(unsigned u) { return __uint_as_float(u << 16); }
__device__ __forceinline__ float hi16f(unsigned u) { return __uint_as_float(u & 0xffff0000u); }
__device__ __forceinline__ unsigned pack2bf(float a, float b) {
  unsigned ua = __float_as_uint(a); ua += 0x7fffu + ((ua >> 16) & 1u);
  unsigned ub = __float_as_uint(b); ub += 0x7fffu + ((ub >> 16) & 1u);
  return (ua >> 16) | (ub & 0xffff0000u);
}
__device__ __forceinline__ float gelu_f(float x) {
  return 0.5f * x * (1.f + erff(x * 0.70710678118654752f));
}

__global__ __launch_bounds__(256) void zero_hist8(int4* __restrict__ h) {
  int i = blockIdx.x * 256 + threadIdx.x;
  if (i < 100000) h[i] = make_int4(0, 0, 0, 0);
}

// pass A: per-edge rank within (dst, seg) bucket. seg = blockIdx&7 (~XCD-local atomics).
__global__ __launch_bounds__(256) void edge_pos(const int* __restrict__ dst,
                                                int* __restrict__ hist8,
                                                int* __restrict__ posrel) {
  int e = blockIdx.x * 256 + threadIdx.x;   // grid exactly covers E
  int d = dst[e];
  int seg = blockIdx.x & 7;
  int r = atomicAdd(&hist8[d * 8 + seg], 1);
  __builtin_nontemporal_store(r, posrel + e);
}

// ---- multi-block exclusive scan over 400000 ints ----
__global__ __launch_bounds__(1024) void scan_partial(const int* __restrict__ hist,
                                                     int* __restrict__ rp,
                                                     int* __restrict__ bsum, int n) {
  __shared__ int wsum[16];
  int tid = threadIdx.x, lane = tid & 63, wv = tid >> 6;
  int i = blockIdx.x * 1024 + tid;
  int v = (i < n) ? hist[i] : 0;
  int sc = v;
  #pragma unroll
  for (int m = 1; m < 64; m <<= 1) { int o = __shfl_up(sc, m); if (lane >= m) sc += o; }
  if (lane == 63) wsum[wv] = sc;
  __syncthreads();
  if (wv == 0) {
    int w = (lane < 16) ? wsum[lane] : 0;
    int swc = w;
    #pragma unroll
    for (int m = 1; m < 16; m <<= 1) { int o = __shfl_up(swc, m); if (lane >= m) swc += o; }
    if (lane < 16) wsum[lane] = swc - w;
    if (lane == 15) bsum[blockIdx.x] = swc;
  }
  __syncthreads();
  if (i < n) rp[i] = (sc - v) + wsum[wv];
}

// single-wave looped scan of block sums (nb up to a few hundred)
__global__ __launch_bounds__(64) void scan_bsums(int* __restrict__ bsum, int nb) {
  int lane = threadIdx.x;
  int carry = 0;
  for (int base = 0; base < nb; base += 64) {
    int i = base + lane;
    int v = (i < nb) ? bsum[i] : 0;
    int sc = v;
    #pragma unroll
    for (int m = 1; m < 64; m <<= 1) { int o = __shfl_up(sc, m); if (lane >= m) sc += o; }
    if (i < nb) bsum[i] = carry + sc - v;
    carry += __shfl(sc, 63);
  }
  if (lane == 0) bsum[nb] = carry;
}

__global__ __launch_bounds__(1024) void scan_add(int* __restrict__ rp,
                                                 const int* __restrict__ bsum, int n) {
  int i = blockIdx.x * 1024 + threadIdx.x;
  if (i < n) rp[i] += bsum[blockIdx.x];
  if (i == 0) rp[n] = bsum[gridDim.x];
}

// dinv from rp8 deltas (deg = sum of a node's 8 shard buckets)
__global__ __launch_bounds__(256) void dinv_kernel(const int* __restrict__ rp8,
                                                   float* __restrict__ dinv, int n) {
  int i = blockIdx.x * 256 + threadIdx.x;
  if (i < n) {
    int deg = rp8[i * 8 + 8] - rp8[i * 8];
    dinv[i] = rsqrtf((float)(deg + 1));  // +1 self loop
  }
}

// pass B: atomic-free scatter into CSR
__global__ __launch_bounds__(256) void fill2(const int* __restrict__ src,
                                             const int* __restrict__ dst,
                                             const int* __restrict__ rp8,
                                             const int* __restrict__ posrel,
                                             int* __restrict__ csr_src) {
  int e = blockIdx.x * 256 + threadIdx.x;
  int s = src[e], d = dst[e];
  int seg = blockIdx.x & 7;
  int pos = rp8[d * 8 + seg] + posrel[e];
  __builtin_nontemporal_store(s, csr_src + pos);
}

// W[K][N] fp32 -> B-frag bf16 hi+lo: flat tid = ((nt*KS+ks)*4+kg)*16 + c15, uint4 per tid.
__global__ __launch_bounds__(256) void convW_split(const float* __restrict__ W,
                                                   unsigned* __restrict__ Wh,
                                                   unsigned* __restrict__ Wl, int K, int N) {
  int tid = blockIdx.x * 256 + threadIdx.x;
  if (tid >= (K * N) / 8) return;
  int c15 = tid & 15;
  int kg  = (tid >> 4) & 3;
  int KS  = K >> 5;
  int ks  = (tid >> 6) % KS;
  int nt  = (tid >> 6) / KS;
  int col = nt * 16 + c15;
  int k0  = ks * 32 + kg * 8;
  float w[8];
  #pragma unroll
  for (int j = 0; j < 8; ++j) w[j] = W[(size_t)(k0 + j) * N + col];
  uint4 h, l;
  h.x = pack2bf(w[0], w[1]); l.x = pack2bf(w[0] - lo16f(h.x), w[1] - hi16f(h.x));
  h.y = pack2bf(w[2], w[3]); l.y = pack2bf(w[2] - lo16f(h.y), w[3] - hi16f(h.y));
  h.z = pack2bf(w[4], w[5]); l.z = pack2bf(w[4] - lo16f(h.z), w[5] - hi16f(h.z));
  h.w = pack2bf(w[6], w[7]); l.w = pack2bf(w[6] - lo16f(h.w), w[7] - hi16f(h.w));
  *reinterpret_cast<uint4*>(Wh + (size_t)tid * 4) = h;
  *reinterpret_cast<uint4*>(Wl + (size_t)tid * 4) = l;
}

// LN over 128, write bf16 table. One wave per row.
__global__ __launch_bounds__(256) void ln1_kernel(const float* __restrict__ x,
                                                  const float* __restrict__ g,
                                                  const float* __restrict__ be,
                                                  unsigned* __restrict__ T) {
  int lane = threadIdx.x & 63, wv = threadIdx.x >> 6;
  int row = blockIdx.x * 4 + wv;
  float2 v = *reinterpret_cast<const float2*>(x + (size_t)row * 128 + lane * 2);
  float s = v.x + v.y, sq = v.x * v.x + v.y * v.y;
  #pragma unroll
  for (int m = 1; m < 64; m <<= 1) { s += __shfl_xor(s, m); sq += __shfl_xor(sq, m); }
  float mu = s * (1.f / 128.f);
  float var = sq * (1.f / 128.f) - mu * mu;
  float rs = rsqrtf(var + 1e-5f);
  float2 gg = *reinterpret_cast<const float2*>(g + lane * 2);
  float2 bb = *reinterpret_cast<const float2*>(be + lane * 2);
  T[(size_t)row * 64 + lane] =
      pack2bf((v.x - mu) * rs * gg.x + bb.x, (v.y - mu) * rs * gg.y + bb.y);
}

// 128-wide aggregation from bf16 table, norm recomputed from dinv. One wave per node.
// MODE 0: write fp32 (no bias)   MODE 2: write fp32 d_out (+bias)
template <int MODE>
__global__ __launch_bounds__(256) void agg128(const unsigned* __restrict__ T,
                                              const int* __restrict__ rp8,
                                              const int* __restrict__ csr_src,
                                              const float* __restrict__ dinv,
                                              const float* __restrict__ b,
                                              float* __restrict__ out) {
  int lane = threadIdx.x & 63, wv = threadIdx.x >> 6;
  int node = blockIdx.x * 4 + wv;
  float di = dinv[node], sn = di * di;
  unsigned us = T[(size_t)node * 64 + lane];
  float a0 = lo16f(us) * sn, a1 = hi16f(us) * sn;
  int e = rp8[node * 8], e1 = rp8[node * 8 + 8];
  for (; e + 3 < e1; e += 4) {
    int4 c = *reinterpret_cast<const int4*>(csr_src + e);
    unsigned u0 = T[(size_t)c.x * 64 + lane];
    unsigned u1 = T[(size_t)c.y * 64 + lane];
    unsigned u2 = T[(size_t)c.z * 64 + lane];
    unsigned u3 = T[(size_t)c.w * 64 + lane];
    float n0 = dinv[c.x] * di, n1 = dinv[c.y] * di;
    float n2 = dinv[c.z] * di, n3 = dinv[c.w] * di;
    a0 += lo16f(u0) * n0; a1 += hi16f(u0) * n0;
    a0 += lo16f(u1) * n1; a1 += hi16f(u1) * n1;
    a0 += lo16f(u2) * n2; a1 += hi16f(u2) * n2;
    a0 += lo16f(u3) * n3; a1 += hi16f(u3) * n3;
  }
  for (; e < e1; ++e) {
    int s = csr_src[e];
    unsigned u = T[(size_t)s * 64 + lane];
    float nr = dinv[s] * di;
    a0 += lo16f(u) * nr; a1 += hi16f(u) * nr;
  }
  if (MODE == 0) {
    *reinterpret_cast<float2*>(out + (size_t)node * 128 + lane * 2) = make_float2(a0, a1);
  } else {
    float2 bb = *reinterpret_cast<const float2*>(b + lane * 2);
    *reinterpret_cast<float2*>(out + (size_t)node * 128 + lane * 2) =
        make_float2(a0 + bb.x, a1 + bb.y);
  }
}

// MFMA GEMM1: fp32[n,128] (split hi/lo on the fly) @ (Wh+Wl) -> +bias, GELU, LN2 -> bf16 [n,256].
__global__ __launch_bounds__(256) void gemm1_fused(const float* __restrict__ A,
                                                   const unsigned* __restrict__ Wh,
                                                   const unsigned* __restrict__ Wl,
                                                   const float* __restrict__ b,
                                                   const float* __restrict__ g,
                                                   const float* __restrict__ be,
                                                   unsigned* __restrict__ T2b, int n) {
  __shared__ float st[32 * 260];
  int t = threadIdx.x, lane = t & 63, w = t >> 6;
  int rtile = (w >> 1) * 16;             // 0 or 16 (block-relative)
  int c0 = (w & 1) * 128;                // 0 or 128
  int arow = blockIdx.x * 32 + rtile + (lane & 15);
  if (arow >= n) arow = n - 1;
  const float* aptr = A + (size_t)arow * 128 + (lane >> 4) * 8;
  f32x4 acc[8];
  #pragma unroll
  for (int nf = 0; nf < 8; ++nf) acc[nf] = (f32x4)(0.f);
  #pragma unroll
  for (int ks = 0; ks < 4; ++ks) {
    float4 v0 = *reinterpret_cast<const float4*>(aptr + ks * 32);
    float4 v1 = *reinterpret_cast<const float4*>(aptr + ks * 32 + 4);
    uint4 h, l;
    h.x = pack2bf(v0.x, v0.y); l.x = pack2bf(v0.x - lo16f(h.x), v0.y - hi16f(h.x));
    h.y = pack2bf(v0.z, v0.w); l.y = pack2bf(v0.z - lo16f(h.y), v0.w - hi16f(h.y));
    h.z = pack2bf(v1.x, v1.y); l.z = pack2bf(v1.x - lo16f(h.z), v1.y - hi16f(h.z));
    h.w = pack2bf(v1.z, v1.w); l.w = pack2bf(v1.z - lo16f(h.w), v1.w - hi16f(h.w));
    s16x8 ah = *reinterpret_cast<s16x8*>(&h);
    s16x8 al = *reinterpret_cast<s16x8*>(&l);
    #pragma unroll
    for (int nf = 0; nf < 8; ++nf) {
      int nt = (c0 >> 4) + nf;
      size_t bo = (size_t)(((nt * 4 + ks) * 4 + (lane >> 4)) * 16 + (lane & 15)) * 4;
      s16x8 bh = *reinterpret_cast<const s16x8*>(Wh + bo);
      s16x8 bl = *reinterpret_cast<const s16x8*>(Wl + bo);
      acc[nf] = __builtin_amdgcn_mfma_f32_16x16x32_bf16(ah, bh, acc[nf], 0, 0, 0);
      acc[nf] = __builtin_amdgcn_mfma_f32_16x16x32_bf16(al, bh, acc[nf], 0, 0, 0);
      acc[nf] = __builtin_amdgcn_mfma_f32_16x16x32_bf16(ah, bl, acc[nf], 0, 0, 0);
    }
  }
  #pragma unroll
  for (int nf = 0; nf < 8; ++nf) {
    int col = c0 + nf * 16 + (lane & 15);
    float bb = b[col];
    #pragma unroll
    for (int r = 0; r < 4; ++r) {
      int row = rtile + (lane >> 4) * 4 + r;
      st[row * 260 + col] = gelu_f(acc[nf][r] + bb);
    }
  }
  __syncthreads();
  float4 gg = *reinterpret_cast<const float4*>(g + lane * 4);
  float4 bb2 = *reinterpret_cast<const float4*>(be + lane * 4);
  #pragma unroll
  for (int rr = 0; rr < 8; ++rr) {
    int row = w * 8 + rr;
    float4 v = *reinterpret_cast<const float4*>(&st[row * 260 + lane * 4]);
    float s = v.x + v.y + v.z + v.w;
    float sq = v.x * v.x + v.y * v.y + v.z * v.z + v.w * v.w;
    #pragma unroll
    for (int m = 1; m < 64; m <<= 1) { s += __shfl_xor(s, m); sq += __shfl_xor(sq, m); }
    float mu = s * (1.f / 256.f);
    float var = sq * (1.f / 256.f) - mu * mu;
    float rs = rsqrtf(var + 1e-5f);
    int gr = blockIdx.x * 32 + row;
    if (gr < n) {
      uint2 p;
      p.x = pack2bf((v.x - mu) * rs * gg.x + bb2.x, (v.y - mu) * rs * gg.y + bb2.y);
      p.y = pack2bf((v.z - mu) * rs * gg.z + bb2.z, (v.w - mu) * rs * gg.w + bb2.w);
      *reinterpret_cast<uint2*>(T2b + (size_t)gr * 128 + lane * 2) = p;
    }
  }
}

// MFMA GEMM2: bf16[n,256] @ (Wh+Wl) -> bf16 table [n,128] (bias deferred to agg2).
__global__ __launch_bounds__(256) void gemm2_mfma(const unsigned* __restrict__ Ab,
                                                  const unsigned* __restrict__ Wh,
                                                  const unsigned* __restrict__ Wl,
                                                  unsigned* __restrict__ T2, int n) {
  __shared__ float st[32 * 132];
  int t = threadIdx.x, lane = t & 63, w = t >> 6;
  int rtile = (w >> 1) * 16;
  int c0 = (w & 1) * 64;
  int arow = blockIdx.x * 32 + rtile + (lane & 15);
  if (arow >= n) arow = n - 1;
  const unsigned* aptr = Ab + (size_t)arow * 128 + (lane >> 4) * 4;
  f32x4 acc[4];
  #pragma unroll
  for (int nf = 0; nf < 4; ++nf) acc[nf] = (f32x4)(0.f);
  #pragma unroll
  for (int ks = 0; ks < 8; ++ks) {
    s16x8 af = *reinterpret_cast<const s16x8*>(aptr + ks * 16);
    #pragma unroll
    for (int nf = 0; nf < 4; ++nf) {
      int nt = (c0 >> 4) + nf;
      size_t bo = (size_t)(((nt * 8 + ks) * 4 + (lane >> 4)) * 16 + (lane & 15)) * 4;
      s16x8 bh = *reinterpret_cast<const s16x8*>(Wh + bo);
      s16x8 bl = *reinterpret_cast<const s16x8*>(Wl + bo);
      acc[nf] = __builtin_amdgcn_mfma_f32_16x16x32_bf16(af, bh, acc[nf], 0, 0, 0);
      acc[nf] = __builtin_amdgcn_mfma_f32_16x16x32_bf16(af, bl, acc[nf], 0, 0, 0);
    }
  }
  #pragma unroll
  for (int nf = 0; nf < 4; ++nf) {
    int col = c0 + nf * 16 + (lane & 15);
    #pragma unroll
    for (int r = 0; r < 4; ++r) {
      int row = rtile + (lane >> 4) * 4 + r;
      st[row * 132 + col] = acc[nf][r];
    }
  }
  __syncthreads();
  #pragma unroll
  for (int rr = 0; rr < 8; ++rr) {
    int row = w * 8 + rr;
    int gr = blockIdx.x * 32 + row;
    if (gr < n) {
      float2 v = *reinterpret_cast<const float2*>(&st[row * 132 + lane * 2]);
      T2[(size_t)gr * 64 + lane] = pack2bf(v.x, v.y);
    }
  }
}

extern "C" void kernel_launch(void* const* d_in, const int* in_sizes, int n_in,
                              void* d_out, int out_size, void* d_ws, size_t ws_size,
                              hipStream_t stream) {
  (void)in_sizes; (void)n_in; (void)out_size; (void)ws_size;
  const float* x   = (const float*)d_in[0];
  const float* W1  = (const float*)d_in[1];
  const float* b1  = (const float*)d_in[2];
  const float* g1  = (const float*)d_in[3];
  const float* be1 = (const float*)d_in[4];
  const float* W4  = (const float*)d_in[5];
  const float* b4  = (const float*)d_in[6];
  const float* g4  = (const float*)d_in[7];
  const float* be4 = (const float*)d_in[8];
  const int*   ei  = (const int*)d_in[9];
  const int* src = ei;
  const int* dst = ei + E_EDGES;

  char* ws = (char*)d_ws;
  unsigned* T1    = (unsigned*)(ws + T1_OFF);
  unsigned* T2    = (unsigned*)(ws + T1_OFF);      // alias: T1 dead after gemm1
  float*    AGG1  = (float*)(ws + AGG1_OFF);
  unsigned* T2b   = (unsigned*)(ws + T2B_OFF);
  unsigned* Wb1h  = (unsigned*)(ws + WB1H_OFF);
  unsigned* Wb1l  = (unsigned*)(ws + WB1L_OFF);
  unsigned* Wb4h  = (unsigned*)(ws + WB4H_OFF);
  unsigned* Wb4l  = (unsigned*)(ws + WB4L_OFF);
  float* dinv     = (float*)(ws + DINV_OFF);
  int*   hist8    = (int*)(ws + HIST8_OFF);
  int*   rp8      = (int*)(ws + RP8_OFF);
  int*   posrel   = (int*)(ws + POSREL_OFF);
  int*   csr_src  = (int*)(ws + CSRS_OFF);
  int*   bsum     = (int*)(ws + BSUM_OFF);
  float* outp     = (float*)d_out;

  const int NSEG = N_NODES * 8;                // 400000
  int nblkE  = E_EDGES / 256;                  // 3125
  int nbScan = (NSEG + 1023) / 1024;           // 391
  int nblkG  = (N_NODES + 31) / 32;            // 1563

  hipLaunchKernelGGL(zero_hist8, dim3(391), dim3(256), 0, stream, (int4*)hist8);
  hipLaunchKernelGGL(edge_pos, dim3(nblkE), dim3(256), 0, stream, dst, hist8, posrel);
  hipLaunchKernelGGL(scan_partial, dim3(nbScan), dim3(1024), 0, stream, hist8, rp8, bsum, NSEG);
  hipLaunchKernelGGL(scan_bsums, dim3(1), dim3(64), 0, stream, bsum, nbScan);
  hipLaunchKernelGGL(scan_add, dim3(nbScan), dim3(1024), 0, stream, rp8, bsum, NSEG);
  hipLaunchKernelGGL(dinv_kernel, dim3((N_NODES + 255) / 256), dim3(256), 0, stream,
                     rp8, dinv, N_NODES);
  hipLaunchKernelGGL(fill2, dim3(nblkE), dim3(256), 0, stream, src, dst, rp8, posrel, csr_src);
  hipLaunchKernelGGL(convW_split, dim3(16), dim3(256), 0, stream, W1, Wb1h, Wb1l, 128, 256);
  hipLaunchKernelGGL(convW_split, dim3(16), dim3(256), 0, stream, W4, Wb4h, Wb4l, 256, 128);

  // Layer 1: LN -> aggregate(128) fp32 -> MFMA GEMM(split) + bias + GELU + LN2 (fused)
  hipLaunchKernelGGL(ln1_kernel, dim3(N_NODES / 4), dim3(256), 0, stream, x, g1, be1, T1);
  hipLaunchKernelGGL(agg128<0>, dim3(N_NODES / 4), dim3(256), 0, stream,
                     T1, rp8, csr_src, dinv, (const float*)nullptr, AGG1);
  hipLaunchKernelGGL(gemm1_fused, dim3(nblkG), dim3(256), 0, stream,
                     AGG1, Wb1h, Wb1l, b1, g4, be4, T2b, N_NODES);

  // Layer 2: MFMA GEMM(W-split) -> aggregate(128)+bias -> out
  hipLaunchKernelGGL(gemm2_mfma, dim3(nblkG), dim3(256), 0, stream, T2b, Wb4h, Wb4l, T2, N_NODES);
  hipLaunchKernelGGL(agg128<2>, dim3(N_NODES / 4), dim3(256), 0, stream,
                     T2, rp8, csr_src, dinv, b4, outp);
}

// Round 6
// 231.857 us; speedup vs baseline: 2.1393x; 1.0092x over previous
//
#include <hip/hip_runtime.h>
#include <math.h>

#define N_NODES 50000
#define E_EDGES 800000

typedef __attribute__((ext_vector_type(4))) float f32x4;
typedef __attribute__((ext_vector_type(8))) short s16x8;

// ---------------- workspace layout (bytes) ----------------
#define T1_OFF    0UL          // bf16 [50000,128] L1 gather table; reused as T2 after gemm1
#define A1H_OFF   12800000UL   // bf16 [50000,128] agg1 output hi (12.8 MB)
#define A1L_OFF   25600000UL   // bf16 [50000,128] agg1 output lo (12.8 MB)
#define T2B_OFF   38400000UL   // bf16 [50000,256] LN2 output (25.6 MB)
#define WB1H_OFF  64000000UL   // W1 B-frag bf16 hi (64 KB)
#define WB1L_OFF  64100096UL
#define WB4H_OFF  64200192UL
#define WB4L_OFF  64300288UL
#define DINV_OFF  64400384UL   // fp32 [50000]
#define HIST8_OFF 64600384UL   // int [50000*8] seg-sharded histogram (1.6 MB)
#define RP8_OFF   66200384UL   // int [50000*8 + 1]
#define POSREL_OFF 67800448UL  // int [E]
#define CSRS_OFF  71000448UL   // int [E]
#define BSUM_OFF  74200448UL

__device__ __forceinline__ float lo16f(unsigned u) { return __uint_as_float(u << 16); }
__device__ __forceinline__ float hi16f(unsigned u) { return __uint_as_float(u & 0xffff0000u); }
__device__ __forceinline__ unsigned pack2bf(float a, float b) {
  unsigned ua = __float_as_uint(a); ua += 0x7fffu + ((ua >> 16) & 1u);
  unsigned ub = __float_as_uint(b); ub += 0x7fffu + ((ub >> 16) & 1u);
  return (ua >> 16) | (ub & 0xffff0000u);
}
__device__ __forceinline__ float gelu_f(float x) {
  return 0.5f * x * (1.f + erff(x * 0.70710678118654752f));
}

__global__ __launch_bounds__(256) void zero_hist8(int4* __restrict__ h) {
  int i = blockIdx.x * 256 + threadIdx.x;
  if (i < 100000) h[i] = make_int4(0, 0, 0, 0);
}

// pass A: per-edge rank within (dst, seg) bucket. seg = blockIdx&7 (~XCD-local atomics).
__global__ __launch_bounds__(256) void edge_pos(const int* __restrict__ dst,
                                                int* __restrict__ hist8,
                                                int* __restrict__ posrel) {
  int e = blockIdx.x * 256 + threadIdx.x;
  int d = dst[e];
  int seg = blockIdx.x & 7;
  int r = atomicAdd(&hist8[d * 8 + seg], 1);
  __builtin_nontemporal_store(r, posrel + e);
}

// ---- multi-block exclusive scan over 400000 ints ----
__global__ __launch_bounds__(1024) void scan_partial(const int* __restrict__ hist,
                                                     int* __restrict__ rp,
                                                     int* __restrict__ bsum, int n) {
  __shared__ int wsum[16];
  int tid = threadIdx.x, lane = tid & 63, wv = tid >> 6;
  int i = blockIdx.x * 1024 + tid;
  int v = (i < n) ? hist[i] : 0;
  int sc = v;
  #pragma unroll
  for (int m = 1; m < 64; m <<= 1) { int o = __shfl_up(sc, m); if (lane >= m) sc += o; }
  if (lane == 63) wsum[wv] = sc;
  __syncthreads();
  if (wv == 0) {
    int w = (lane < 16) ? wsum[lane] : 0;
    int swc = w;
    #pragma unroll
    for (int m = 1; m < 16; m <<= 1) { int o = __shfl_up(swc, m); if (lane >= m) swc += o; }
    if (lane < 16) wsum[lane] = swc - w;
    if (lane == 15) bsum[blockIdx.x] = swc;
  }
  __syncthreads();
  if (i < n) rp[i] = (sc - v) + wsum[wv];
}

__global__ __launch_bounds__(64) void scan_bsums(int* __restrict__ bsum, int nb) {
  int lane = threadIdx.x;
  int carry = 0;
  for (int base = 0; base < nb; base += 64) {
    int i = base + lane;
    int v = (i < nb) ? bsum[i] : 0;
    int sc = v;
    #pragma unroll
    for (int m = 1; m < 64; m <<= 1) { int o = __shfl_up(sc, m); if (lane >= m) sc += o; }
    if (i < nb) bsum[i] = carry + sc - v;
    carry += __shfl(sc, 63);
  }
  if (lane == 0) bsum[nb] = carry;
}

__global__ __launch_bounds__(1024) void scan_add(int* __restrict__ rp,
                                                 const int* __restrict__ bsum, int n) {
  int i = blockIdx.x * 1024 + threadIdx.x;
  if (i < n) rp[i] += bsum[blockIdx.x];
  if (i == 0) rp[n] = bsum[gridDim.x];
}

// dinv from pre-scan hist8 sums (independent of the scan)
__global__ __launch_bounds__(256) void dinv_kernel(const int* __restrict__ hist8,
                                                   float* __restrict__ dinv, int n) {
  int i = blockIdx.x * 256 + threadIdx.x;
  if (i < n) {
    int4 a = *reinterpret_cast<const int4*>(hist8 + i * 8);
    int4 b = *reinterpret_cast<const int4*>(hist8 + i * 8 + 4);
    int deg = a.x + a.y + a.z + a.w + b.x + b.y + b.z + b.w;
    dinv[i] = rsqrtf((float)(deg + 1));  // +1 self loop
  }
}

// pass B: atomic-free scatter into CSR
__global__ __launch_bounds__(256) void fill2(const int* __restrict__ src,
                                             const int* __restrict__ dst,
                                             const int* __restrict__ rp8,
                                             const int* __restrict__ posrel,
                                             int* __restrict__ csr_src) {
  int e = blockIdx.x * 256 + threadIdx.x;
  int s = src[e], d = dst[e];
  int seg = blockIdx.x & 7;
  int pos = rp8[d * 8 + seg] + posrel[e];
  __builtin_nontemporal_store(s, csr_src + pos);
}

// W[K][N] fp32 -> B-frag bf16 hi+lo: flat tid = ((nt*KS+ks)*4+kg)*16 + c15, uint4 per tid.
__global__ __launch_bounds__(256) void convW_split(const float* __restrict__ W,
                                                   unsigned* __restrict__ Wh,
                                                   unsigned* __restrict__ Wl, int K, int N) {
  int tid = blockIdx.x * 256 + threadIdx.x;
  if (tid >= (K * N) / 8) return;
  int c15 = tid & 15;
  int kg  = (tid >> 4) & 3;
  int KS  = K >> 5;
  int ks  = (tid >> 6) % KS;
  int nt  = (tid >> 6) / KS;
  int col = nt * 16 + c15;
  int k0  = ks * 32 + kg * 8;
  float w[8];
  #pragma unroll
  for (int j = 0; j < 8; ++j) w[j] = W[(size_t)(k0 + j) * N + col];
  uint4 h, l;
  h.x = pack2bf(w[0], w[1]); l.x = pack2bf(w[0] - lo16f(h.x), w[1] - hi16f(h.x));
  h.y = pack2bf(w[2], w[3]); l.y = pack2bf(w[2] - lo16f(h.y), w[3] - hi16f(h.y));
  h.z = pack2bf(w[4], w[5]); l.z = pack2bf(w[4] - lo16f(h.z), w[5] - hi16f(h.z));
  h.w = pack2bf(w[6], w[7]); l.w = pack2bf(w[6] - lo16f(h.w), w[7] - hi16f(h.w));
  *reinterpret_cast<uint4*>(Wh + (size_t)tid * 4) = h;
  *reinterpret_cast<uint4*>(Wl + (size_t)tid * 4) = l;
}

// LN over 128, write bf16 table. One wave per row.
__global__ __launch_bounds__(256) void ln1_kernel(const float* __restrict__ x,
                                                  const float* __restrict__ g,
                                                  const float* __restrict__ be,
                                                  unsigned* __restrict__ T) {
  int lane = threadIdx.x & 63, wv = threadIdx.x >> 6;
  int row = blockIdx.x * 4 + wv;
  float2 v = *reinterpret_cast<const float2*>(x + (size_t)row * 128 + lane * 2);
  float s = v.x + v.y, sq = v.x * v.x + v.y * v.y;
  #pragma unroll
  for (int m = 1; m < 64; m <<= 1) { s += __shfl_xor(s, m); sq += __shfl_xor(sq, m); }
  float mu = s * (1.f / 128.f);
  float var = sq * (1.f / 128.f) - mu * mu;
  float rs = rsqrtf(var + 1e-5f);
  float2 gg = *reinterpret_cast<const float2*>(g + lane * 2);
  float2 bb = *reinterpret_cast<const float2*>(be + lane * 2);
  T[(size_t)row * 64 + lane] =
      pack2bf((v.x - mu) * rs * gg.x + bb.x, (v.y - mu) * rs * gg.y + bb.y);
}

// 128-wide aggregation from bf16 table. One wave per node.
// MODE 0: write bf16 hi+lo tables (no bias)   MODE 2: write fp32 d_out (+bias)
template <int MODE>
__global__ __launch_bounds__(256) void agg128(const unsigned* __restrict__ T,
                                              const int* __restrict__ rp8,
                                              const int* __restrict__ csr_src,
                                              const float* __restrict__ dinv,
                                              const float* __restrict__ b,
                                              float* __restrict__ out,
                                              unsigned* __restrict__ outh,
                                              unsigned* __restrict__ outl) {
  int lane = threadIdx.x & 63, wv = threadIdx.x >> 6;
  int node = blockIdx.x * 4 + wv;
  float di = dinv[node], sn = di * di;
  unsigned us = T[(size_t)node * 64 + lane];
  float a0 = lo16f(us) * sn, a1 = hi16f(us) * sn;
  int e = rp8[node * 8], e1 = rp8[node * 8 + 8];
  for (; e + 3 < e1; e += 4) {
    int4 c = *reinterpret_cast<const int4*>(csr_src + e);
    unsigned u0 = T[(size_t)c.x * 64 + lane];
    unsigned u1 = T[(size_t)c.y * 64 + lane];
    unsigned u2 = T[(size_t)c.z * 64 + lane];
    unsigned u3 = T[(size_t)c.w * 64 + lane];
    float n0 = dinv[c.x] * di, n1 = dinv[c.y] * di;
    float n2 = dinv[c.z] * di, n3 = dinv[c.w] * di;
    a0 += lo16f(u0) * n0; a1 += hi16f(u0) * n0;
    a0 += lo16f(u1) * n1; a1 += hi16f(u1) * n1;
    a0 += lo16f(u2) * n2; a1 += hi16f(u2) * n2;
    a0 += lo16f(u3) * n3; a1 += hi16f(u3) * n3;
  }
  for (; e < e1; ++e) {
    int s = csr_src[e];
    unsigned u = T[(size_t)s * 64 + lane];
    float nr = dinv[s] * di;
    a0 += lo16f(u) * nr; a1 += hi16f(u) * nr;
  }
  if (MODE == 0) {
    unsigned h = pack2bf(a0, a1);
    float r0 = a0 - lo16f(h), r1 = a1 - hi16f(h);
    outh[(size_t)node * 64 + lane] = h;
    outl[(size_t)node * 64 + lane] = pack2bf(r0, r1);
  } else {
    float2 bb = *reinterpret_cast<const float2*>(b + lane * 2);
    *reinterpret_cast<float2*>(out + (size_t)node * 128 + lane * 2) =
        make_float2(a0 + bb.x, a1 + bb.y);
  }
}

// MFMA GEMM1: bf16 hi/lo A @ (Wh+Wl) -> +bias, GELU, LN2 -> bf16 [n,256].
// 32 rows/block, wave owns 64 cols (4 nf), W frags held across 2 row-tiles.
__global__ __launch_bounds__(256) void gemm1_fused(const unsigned* __restrict__ Ah,
                                                   const unsigned* __restrict__ Al,
                                                   const unsigned* __restrict__ Wh,
                                                   const unsigned* __restrict__ Wl,
                                                   const float* __restrict__ b,
                                                   const float* __restrict__ g,
                                                   const float* __restrict__ be,
                                                   unsigned* __restrict__ T2b, int n) {
  __shared__ float st[32 * 260];
  int t = threadIdx.x, lane = t & 63, w = t >> 6;
  int kg = lane >> 4, c15 = lane & 15;
  int c0 = w * 64;                         // wave's col base (4 nf)
  int row0 = blockIdx.x * 32 + c15;
  int r0 = min(row0, n - 1);
  int r1 = min(row0 + 16, n - 1);
  const unsigned* ah0 = Ah + (size_t)r0 * 64 + kg * 4;
  const unsigned* al0 = Al + (size_t)r0 * 64 + kg * 4;
  const unsigned* ah1 = Ah + (size_t)r1 * 64 + kg * 4;
  const unsigned* al1 = Al + (size_t)r1 * 64 + kg * 4;
  f32x4 acc[2][4];
  #pragma unroll
  for (int rt = 0; rt < 2; ++rt)
    #pragma unroll
    for (int nf = 0; nf < 4; ++nf) acc[rt][nf] = (f32x4)(0.f);
  #pragma unroll
  for (int ks = 0; ks < 4; ++ks) {
    s16x8 bh[4], bl[4];
    #pragma unroll
    for (int nf = 0; nf < 4; ++nf) {
      int nt = (c0 >> 4) + nf;
      size_t bo = (size_t)(((nt * 4 + ks) * 4 + kg) * 16 + c15) * 4;
      bh[nf] = *reinterpret_cast<const s16x8*>(Wh + bo);
      bl[nf] = *reinterpret_cast<const s16x8*>(Wl + bo);
    }
    s16x8 a0h = *reinterpret_cast<const s16x8*>(ah0 + ks * 16);
    s16x8 a0l = *reinterpret_cast<const s16x8*>(al0 + ks * 16);
    s16x8 a1h = *reinterpret_cast<const s16x8*>(ah1 + ks * 16);
    s16x8 a1l = *reinterpret_cast<const s16x8*>(al1 + ks * 16);
    #pragma unroll
    for (int nf = 0; nf < 4; ++nf) {
      acc[0][nf] = __builtin_amdgcn_mfma_f32_16x16x32_bf16(a0h, bh[nf], acc[0][nf], 0, 0, 0);
      acc[0][nf] = __builtin_amdgcn_mfma_f32_16x16x32_bf16(a0l, bh[nf], acc[0][nf], 0, 0, 0);
      acc[0][nf] = __builtin_amdgcn_mfma_f32_16x16x32_bf16(a0h, bl[nf], acc[0][nf], 0, 0, 0);
      acc[1][nf] = __builtin_amdgcn_mfma_f32_16x16x32_bf16(a1h, bh[nf], acc[1][nf], 0, 0, 0);
      acc[1][nf] = __builtin_amdgcn_mfma_f32_16x16x32_bf16(a1l, bh[nf], acc[1][nf], 0, 0, 0);
      acc[1][nf] = __builtin_amdgcn_mfma_f32_16x16x32_bf16(a1h, bl[nf], acc[1][nf], 0, 0, 0);
    }
  }
  #pragma unroll
  for (int rt = 0; rt < 2; ++rt)
    #pragma unroll
    for (int nf = 0; nf < 4; ++nf) {
      int col = c0 + nf * 16 + c15;
      float bb = b[col];
      #pragma unroll
      for (int r = 0; r < 4; ++r) {
        int row = rt * 16 + kg * 4 + r;
        st[row * 260 + col] = gelu_f(acc[rt][nf][r] + bb);
      }
    }
  __syncthreads();
  float4 gg = *reinterpret_cast<const float4*>(g + lane * 4);
  float4 bb2 = *reinterpret_cast<const float4*>(be + lane * 4);
  #pragma unroll
  for (int rr = 0; rr < 8; ++rr) {
    int row = w * 8 + rr;
    float4 v = *reinterpret_cast<const float4*>(&st[row * 260 + lane * 4]);
    float s = v.x + v.y + v.z + v.w;
    float sq = v.x * v.x + v.y * v.y + v.z * v.z + v.w * v.w;
    #pragma unroll
    for (int m = 1; m < 64; m <<= 1) { s += __shfl_xor(s, m); sq += __shfl_xor(sq, m); }
    float mu = s * (1.f / 256.f);
    float var = sq * (1.f / 256.f) - mu * mu;
    float rs = rsqrtf(var + 1e-5f);
    int gr = blockIdx.x * 32 + row;
    if (gr < n) {
      uint2 p;
      p.x = pack2bf((v.x - mu) * rs * gg.x + bb2.x, (v.y - mu) * rs * gg.y + bb2.y);
      p.y = pack2bf((v.z - mu) * rs * gg.z + bb2.z, (v.w - mu) * rs * gg.w + bb2.w);
      *reinterpret_cast<uint2*>(T2b + (size_t)gr * 128 + lane * 2) = p;
    }
  }
}

// MFMA GEMM2: bf16[n,256] @ (Wh+Wl) -> bf16 table [n,128].
// 32 rows/block, wave owns 32 cols (2 nf), W frags held across 2 row-tiles.
__global__ __launch_bounds__(256) void gemm2_mfma(const unsigned* __restrict__ Ab,
                                                  const unsigned* __restrict__ Wh,
                                                  const unsigned* __restrict__ Wl,
                                                  unsigned* __restrict__ T2, int n) {
  __shared__ float st[32 * 132];
  int t = threadIdx.x, lane = t & 63, w = t >> 6;
  int kg = lane >> 4, c15 = lane & 15;
  int c0 = w * 32;                         // wave's col base (2 nf)
  int row0 = blockIdx.x * 32 + c15;
  int r0 = min(row0, n - 1);
  int r1 = min(row0 + 16, n - 1);
  const unsigned* ap0 = Ab + (size_t)r0 * 128 + kg * 4;
  const unsigned* ap1 = Ab + (size_t)r1 * 128 + kg * 4;
  f32x4 acc[2][2];
  #pragma unroll
  for (int rt = 0; rt < 2; ++rt) { acc[rt][0] = (f32x4)(0.f); acc[rt][1] = (f32x4)(0.f); }
  #pragma unroll
  for (int ks = 0; ks < 8; ++ks) {
    s16x8 bh[2], bl[2];
    #pragma unroll
    for (int nf = 0; nf < 2; ++nf) {
      int nt = (c0 >> 4) + nf;
      size_t bo = (size_t)(((nt * 8 + ks) * 4 + kg) * 16 + c15) * 4;
      bh[nf] = *reinterpret_cast<const s16x8*>(Wh + bo);
      bl[nf] = *reinterpret_cast<const s16x8*>(Wl + bo);
    }
    s16x8 a0 = *reinterpret_cast<const s16x8*>(ap0 + ks * 16);
    s16x8 a1 = *reinterpret_cast<const s16x8*>(ap1 + ks * 16);
    #pragma unroll
    for (int nf = 0; nf < 2; ++nf) {
      acc[0][nf] = __builtin_amdgcn_mfma_f32_16x16x32_bf16(a0, bh[nf], acc[0][nf], 0, 0, 0);
      acc[0][nf] = __builtin_amdgcn_mfma_f32_16x16x32_bf16(a0, bl[nf], acc[0][nf], 0, 0, 0);
      acc[1][nf] = __builtin_amdgcn_mfma_f32_16x16x32_bf16(a1, bh[nf], acc[1][nf], 0, 0, 0);
      acc[1][nf] = __builtin_amdgcn_mfma_f32_16x16x32_bf16(a1, bl[nf], acc[1][nf], 0, 0, 0);
    }
  }
  #pragma unroll
  for (int rt = 0; rt < 2; ++rt)
    #pragma unroll
    for (int nf = 0; nf < 2; ++nf) {
      int col = c0 + nf * 16 + c15;
      #pragma unroll
      for (int r = 0; r < 4; ++r) {
        int row = rt * 16 + kg * 4 + r;
        st[row * 132 + col] = acc[rt][nf][r];
      }
    }
  __syncthreads();
  #pragma unroll
  for (int rr = 0; rr < 8; ++rr) {
    int row = w * 8 + rr;
    int gr = blockIdx.x * 32 + row;
    if (gr < n) {
      float2 v = *reinterpret_cast<const float2*>(&st[row * 132 + lane * 2]);
      T2[(size_t)gr * 64 + lane] = pack2bf(v.x, v.y);
    }
  }
}

extern "C" void kernel_launch(void* const* d_in, const int* in_sizes, int n_in,
                              void* d_out, int out_size, void* d_ws, size_t ws_size,
                              hipStream_t stream) {
  (void)in_sizes; (void)n_in; (void)out_size; (void)ws_size;
  const float* x   = (const float*)d_in[0];
  const float* W1  = (const float*)d_in[1];
  const float* b1  = (const float*)d_in[2];
  const float* g1  = (const float*)d_in[3];
  const float* be1 = (const float*)d_in[4];
  const float* W4  = (const float*)d_in[5];
  const float* b4  = (const float*)d_in[6];
  const float* g4  = (const float*)d_in[7];
  const float* be4 = (const float*)d_in[8];
  const int*   ei  = (const int*)d_in[9];
  const int* src = ei;
  const int* dst = ei + E_EDGES;

  char* ws = (char*)d_ws;
  unsigned* T1    = (unsigned*)(ws + T1_OFF);
  unsigned* T2    = (unsigned*)(ws + T1_OFF);      // alias: T1 dead after gemm1
  unsigned* A1h   = (unsigned*)(ws + A1H_OFF);
  unsigned* A1l   = (unsigned*)(ws + A1L_OFF);
  unsigned* T2b   = (unsigned*)(ws + T2B_OFF);
  unsigned* Wb1h  = (unsigned*)(ws + WB1H_OFF);
  unsigned* Wb1l  = (unsigned*)(ws + WB1L_OFF);
  unsigned* Wb4h  = (unsigned*)(ws + WB4H_OFF);
  unsigned* Wb4l  = (unsigned*)(ws + WB4L_OFF);
  float* dinv     = (float*)(ws + DINV_OFF);
  int*   hist8    = (int*)(ws + HIST8_OFF);
  int*   rp8      = (int*)(ws + RP8_OFF);
  int*   posrel   = (int*)(ws + POSREL_OFF);
  int*   csr_src  = (int*)(ws + CSRS_OFF);
  int*   bsum     = (int*)(ws + BSUM_OFF);
  float* outp     = (float*)d_out;

  const int NSEG = N_NODES * 8;                // 400000
  int nblkE  = E_EDGES / 256;                  // 3125
  int nbScan = (NSEG + 1023) / 1024;           // 391
  int nblkG  = (N_NODES + 31) / 32;            // 1563

  hipLaunchKernelGGL(zero_hist8, dim3(391), dim3(256), 0, stream, (int4*)hist8);
  hipLaunchKernelGGL(edge_pos, dim3(nblkE), dim3(256), 0, stream, dst, hist8, posrel);
  hipLaunchKernelGGL(dinv_kernel, dim3((N_NODES + 255) / 256), dim3(256), 0, stream,
                     hist8, dinv, N_NODES);
  hipLaunchKernelGGL(scan_partial, dim3(nbScan), dim3(1024), 0, stream, hist8, rp8, bsum, NSEG);
  hipLaunchKernelGGL(scan_bsums, dim3(1), dim3(64), 0, stream, bsum, nbScan);
  hipLaunchKernelGGL(scan_add, dim3(nbScan), dim3(1024), 0, stream, rp8, bsum, NSEG);
  hipLaunchKernelGGL(fill2, dim3(nblkE), dim3(256), 0, stream, src, dst, rp8, posrel, csr_src);
  hipLaunchKernelGGL(convW_split, dim3(16), dim3(256), 0, stream, W1, Wb1h, Wb1l, 128, 256);
  hipLaunchKernelGGL(convW_split, dim3(16), dim3(256), 0, stream, W4, Wb4h, Wb4l, 256, 128);

  // Layer 1: LN -> aggregate(128) -> hi/lo split -> MFMA GEMM + bias + GELU + LN2 (fused)
  hipLaunchKernelGGL(ln1_kernel, dim3(N_NODES / 4), dim3(256), 0, stream, x, g1, be1, T1);
  hipLaunchKernelGGL(agg128<0>, dim3(N_NODES / 4), dim3(256), 0, stream,
                     T1, rp8, csr_src, dinv, (const float*)nullptr,
                     (float*)nullptr, A1h, A1l);
  hipLaunchKernelGGL(gemm1_fused, dim3(nblkG), dim3(256), 0, stream,
                     A1h, A1l, Wb1h, Wb1l, b1, g4, be4, T2b, N_NODES);

  // Layer 2: MFMA GEMM(W-split) -> aggregate(128)+bias -> out
  hipLaunchKernelGGL(gemm2_mfma, dim3(nblkG), dim3(256), 0, stream, T2b, Wb4h, Wb4l, T2, N_NODES);
  hipLaunchKernelGGL(agg128<2>, dim3(N_NODES / 4), dim3(256), 0, stream,
                     T2, rp8, csr_src, dinv, b4, outp,
                     (unsigned*)nullptr, (unsigned*)nullptr);
}